// Round 1
// baseline (1280.520 us; speedup 1.0000x reference)
//
#include <hip/hip_runtime.h>
#include <hip/hip_bf16.h>
#include <cstdint>
#include <cstddef>

typedef __bf16 bf16;
typedef __bf16 bf16x8 __attribute__((ext_vector_type(8)));
typedef float f32x4 __attribute__((ext_vector_type(4)));

// ---------------- weight repack: w[OC][IC][NT] -> out[OC][NT*IC] bf16 (k = tap*IC + ic)
__global__ void __launch_bounds__(256) repack_w(const float* __restrict__ w, bf16* __restrict__ out,
                                                int OC, int IC, int NT) {
    int idx = blockIdx.x * 256 + threadIdx.x;
    int total = OC * IC * NT;
    if (idx >= total) return;
    int oc = idx / (NT * IC);
    int rem = idx - oc * NT * IC;
    int tap = rem / IC;
    int ic  = rem - tap * IC;
    out[idx] = (bf16)w[((size_t)oc * IC + ic) * NT + tap];
}

// ---------------- fc1_w [2304][1024] -> fc1t [1024][2304] bf16
__global__ void __launch_bounds__(256) transpose_fc1(const float* __restrict__ w, bf16* __restrict__ out) {
    int idx = blockIdx.x * 256 + threadIdx.x;
    if (idx >= 1024 * 2304) return;
    int o = idx / 2304;
    int i = idx - o * 2304;
    out[idx] = (bf16)w[(size_t)i * 1024 + o];
}

// ---------------- BN fold: s = g*rsqrt(v+eps), t = b - m*s
__global__ void __launch_bounds__(256) bn_fold(const float* __restrict__ g, const float* __restrict__ b,
                                               const float* __restrict__ m, const float* __restrict__ v,
                                               float* __restrict__ s, float* __restrict__ t, int n) {
    int i = blockIdx.x * 256 + threadIdx.x;
    if (i >= n) return;
    float sc = g[i] * rsqrtf(v[i] + 1e-5f);
    s[i] = sc;
    t[i] = b[i] - m[i] * sc;
}

// ---------------- rowbase arrays for the 4 GEMMs
__global__ void __launch_bounds__(256) setup_rowbase(int* __restrict__ rb1, int* __restrict__ rb2,
                                                     int* __restrict__ rb1d, int* __restrict__ rbfc,
                                                     const int* __restrict__ pidx) {
    int m = blockIdx.x * 256 + threadIdx.x;
    if (m < 9856) {                       // conv1/conv2: M=9792 padded to 77*128
        int mm = m < 9792 ? m : 0;
        int img = mm / 9, pos = mm - img * 9;
        int base = img * 25 + (pos / 3) * 5 + (pos % 3);   // padded 5x5, tap (0,0) origin
        rb1[m] = base * 1024;
        rb2[m] = base * 512;
    }
    if (m < 1280) {                       // conv1d rows: m = p*64 + t
        int p = m >> 6, t = m & 63;
        rb1d[m] = (p * 66 + t) * 2304;
    }
    if (m < 1024) {                       // fc1 rows: m = b*16 + n_, gather person_idx
        int b = m >> 4;
        rbfc[m] = (b * 20 + pidx[m]) * 2304;
    }
}

// ---------------- roi_align -> apad1[1088][5][5][1024] bf16 (interior 3x3, border pre-zeroed)
__global__ void __launch_bounds__(256) roi_kernel(const float* __restrict__ fmap, const float* __restrict__ boxes,
                                                  bf16* __restrict__ apad) {
    int box = blockIdx.x;
    int c = blockIdx.y * 256 + threadIdx.x;
    float x1, y1, x2, y2;
    int img;
    if (box < 64) { img = box; x1 = 0.f; y1 = 0.f; x2 = 14.f; y2 = 14.f; }
    else {
        int ib = box - 64;
        img = ib >> 4;
        const float* bb = boxes + (size_t)ib * 4;
        x1 = bb[0]; y1 = bb[1]; x2 = bb[2]; y2 = bb[3];
    }
    float rw = fmaxf(x2 - x1, 1.f), rh = fmaxf(y2 - y1, 1.f);
    __shared__ float swy[6], swx[6];
    __shared__ int sy0[6], sx0[6];
    if (threadIdx.x < 6) {
        int i = threadIdx.x;
        float pos = ((float)i + 0.5f) * 0.5f;
        float yv = fminf(fmaxf(y1 + pos * (rh * (1.f / 3.f)), 0.f), 13.f);
        float y0 = floorf(yv);
        sy0[i] = (int)y0; swy[i] = yv - y0;
        float xv = fminf(fmaxf(x1 + pos * (rw * (1.f / 3.f)), 0.f), 13.f);
        float x0 = floorf(xv);
        sx0[i] = (int)x0; swx[i] = xv - x0;
    }
    __syncthreads();
    const float* fm = fmap + ((size_t)img * 1024 + c) * 196;
    #pragma unroll
    for (int oy = 0; oy < 3; oy++) {
        #pragma unroll
        for (int ox = 0; ox < 3; ox++) {
            float acc = 0.f;
            #pragma unroll
            for (int dy = 0; dy < 2; dy++) {
                int sy = 2 * oy + dy;
                int y0 = sy0[sy]; float wy = swy[sy];
                int y1i = min(y0 + 1, 13);
                #pragma unroll
                for (int dx = 0; dx < 2; dx++) {
                    int sx = 2 * ox + dx;
                    int x0 = sx0[sx]; float wx = swx[sx];
                    int x1i = min(x0 + 1, 13);
                    float f00 = fm[y0 * 14 + x0], f01 = fm[y0 * 14 + x1i];
                    float f10 = fm[y1i * 14 + x0], f11 = fm[y1i * 14 + x1i];
                    acc += f00 * (1.f - wy) * (1.f - wx) + f01 * (1.f - wy) * wx
                         + f10 * wy * (1.f - wx) + f11 * wy * wx;
                }
            }
            apad[((size_t)box * 25 + (oy + 1) * 5 + (ox + 1)) * 1024 + c] = (bf16)(acc * 0.25f);
        }
    }
}

// ---------------- behavior assembly: bpad[p][t+1][f] = g_feat[t] + sum_{n: idx==p} i_feat[t,n]
__global__ void __launch_bounds__(256) assemble(const float* __restrict__ feat, const int* __restrict__ pidx,
                                                bf16* __restrict__ bpad) {
    int b = blockIdx.x;   // 0..63 (time index)
    int p = blockIdx.y;   // 0..19
    __shared__ int idxs[16];
    if (threadIdx.x < 16) idxs[threadIdx.x] = pidx[b * 16 + threadIdx.x];
    __syncthreads();
    const float* g = feat + (size_t)b * 2304;
    for (int f = threadIdx.x; f < 2304; f += 256) {
        float v = g[f];
        #pragma unroll
        for (int n = 0; n < 16; n++)
            if (idxs[n] == p) v += feat[(size_t)(64 + b * 16 + n) * 2304 + f];
        bpad[((size_t)p * 66 + (b + 1)) * 2304 + f] = (bf16)v;
    }
}

// ---------------- unified implicit-GEMM MFMA kernel
// C[M][N] = sum_k A[rowbase[m] + posOff(k/Cin)*Cin + k%Cin] * B[n*K + k]
// BM=128, BN=64, BK=64; 4 waves, each wave: 32 rows x 64 cols (2x4 16x16x32 tiles)
template <int MODE>
__global__ void __launch_bounds__(256) gemm_k(const bf16* __restrict__ A, const int* __restrict__ rowbase,
                                              const bf16* __restrict__ Bw, void* __restrict__ outp,
                                              const float* __restrict__ c0, const float* __restrict__ c1) {
    constexpr int K   = MODE == 0 ? 9216 : MODE == 1 ? 4608 : MODE == 2 ? 6912 : 2304;
    constexpr int Cin = MODE == 0 ? 1024 : MODE == 1 ? 512  : 2304;
    constexpr int M   = MODE <= 1 ? 9792 : MODE == 2 ? 1280 : 1024;
    constexpr bool C3 = (MODE <= 1);
    constexpr bool MPAD = (M % 128) != 0;

    const int bm = blockIdx.y * 128;
    const int bn = blockIdx.x * 64;
    const int tid = threadIdx.x;
    const int lane = tid & 63, wave = tid >> 6;
    const int q = lane >> 4, ln16 = lane & 15;

    __shared__ __align__(16) bf16 As[128 * 72];
    __shared__ __align__(16) bf16 Bs[64 * 72];
    __shared__ int rb[128];

    if (tid < 128) rb[tid] = rowbase[bm + tid];

    f32x4 acc[2][4];
    #pragma unroll
    for (int mt = 0; mt < 2; mt++)
        #pragma unroll
        for (int nt = 0; nt < 4; nt++)
            acc[mt][nt] = (f32x4){0.f, 0.f, 0.f, 0.f};

    for (int kt = 0; kt < K / 64; kt++) {
        const int k0 = kt * 64;
        const int tap = k0 / Cin;                 // constexpr divisor -> cheap
        const int inner = k0 - tap * Cin;
        const int poff = C3 ? ((tap / 3) * 5 + (tap % 3)) : tap;
        const int aoff = poff * Cin + inner;

        __syncthreads();   // protect LDS (and rb on iter 0) before overwrite
        #pragma unroll
        for (int u = 0; u < 4; u++) {            // stage A: 128 rows x 8 chunks
            int id = tid + u * 256;
            int row = id >> 3, c = id & 7;
            const bf16* src = A + (size_t)(rb[row] + aoff + c * 8);
            *(bf16x8*)(As + row * 72 + c * 8) = *(const bf16x8*)src;
        }
        #pragma unroll
        for (int u = 0; u < 2; u++) {            // stage B: 64 rows x 8 chunks
            int id = tid + u * 256;
            int row = id >> 3, c = id & 7;
            const bf16* src = Bw + (size_t)(bn + row) * K + k0 + c * 8;
            *(bf16x8*)(Bs + row * 72 + c * 8) = *(const bf16x8*)src;
        }
        __syncthreads();

        #pragma unroll
        for (int s = 0; s < 2; s++) {
            bf16x8 af[2], bfr[4];
            #pragma unroll
            for (int mt = 0; mt < 2; mt++)
                af[mt] = *(const bf16x8*)(As + (wave * 32 + mt * 16 + ln16) * 72 + s * 32 + q * 8);
            #pragma unroll
            for (int nt = 0; nt < 4; nt++)
                bfr[nt] = *(const bf16x8*)(Bs + (nt * 16 + ln16) * 72 + s * 32 + q * 8);
            #pragma unroll
            for (int mt = 0; mt < 2; mt++)
                #pragma unroll
                for (int nt = 0; nt < 4; nt++)
                    acc[mt][nt] = __builtin_amdgcn_mfma_f32_16x16x32_bf16(af[mt], bfr[nt], acc[mt][nt], 0, 0, 0);
        }
    }

    // epilogue: C/D layout col=lane&15, row=quad*4+reg
    #pragma unroll
    for (int mt = 0; mt < 2; mt++) {
        int gmBase = bm + wave * 32 + mt * 16 + q * 4;
        #pragma unroll
        for (int r = 0; r < 4; r++) {
            int gm = gmBase + r;
            if (MPAD && gm >= M) continue;
            #pragma unroll
            for (int nt = 0; nt < 4; nt++) {
                int gn = bn + nt * 16 + ln16;
                float v = acc[mt][nt][r];
                if constexpr (MODE == 0) {        // conv1: BN+leaky -> apad2 bf16 interior
                    v = v * c0[gn] + c1[gn];
                    v = v > 0.f ? v : 0.1f * v;
                    int img = gm / 9, pos = gm - img * 9;
                    ((bf16*)outp)[(size_t)(img * 25 + (pos / 3 + 1) * 5 + (pos % 3 + 1)) * 512 + gn] = (bf16)v;
                } else if constexpr (MODE == 1) { // conv2: BN+leaky -> feat fp32 [img][oc*9+pos]
                    v = v * c0[gn] + c1[gn];
                    v = v > 0.f ? v : 0.1f * v;
                    int img = gm / 9, pos = gm - img * 9;
                    ((float*)outp)[(size_t)img * 2304 + gn * 9 + pos] = v;
                } else if constexpr (MODE == 2) { // conv1d: +bias -> xbuf[t][p][oc] bf16
                    v += c0[gn];
                    int p = gm >> 6, t = gm & 63;
                    ((bf16*)outp)[(size_t)(t * 20 + p) * 2304 + gn] = (bf16)v;
                } else {                          // fc1: +bias, relu -> hbuf bf16
                    v = fmaxf(v + c0[gn], 0.f);
                    ((bf16*)outp)[(size_t)gm * 1024 + gn] = (bf16)v;
                }
            }
        }
    }
}

// ---------------- fc2: out[1024][30] = h[1024][1024] @ w2[1024][30] + b2
__global__ void __launch_bounds__(256) fc2_kernel(const bf16* __restrict__ h, const float* __restrict__ w2,
                                                  const float* __restrict__ b2, float* __restrict__ out) {
    int idx = blockIdx.x * 256 + threadIdx.x;
    if (idx >= 1024 * 30) return;
    int m = idx / 30, n = idx - m * 30;
    const bf16* hr = h + (size_t)m * 1024;
    float a0 = 0.f, a1 = 0.f, a2 = 0.f, a3 = 0.f;
    for (int k = 0; k < 1024; k += 4) {
        a0 += (float)hr[k]     * w2[(size_t)k * 30 + n];
        a1 += (float)hr[k + 1] * w2[(size_t)(k + 1) * 30 + n];
        a2 += (float)hr[k + 2] * w2[(size_t)(k + 2) * 30 + n];
        a3 += (float)hr[k + 3] * w2[(size_t)(k + 3) * 30 + n];
    }
    out[idx] = a0 + a1 + a2 + a3 + b2[n];
}

extern "C" void kernel_launch(void* const* d_in, const int* in_sizes, int n_in,
                              void* d_out, int out_size, void* d_ws, size_t ws_size,
                              hipStream_t stream) {
    const float* fmap     = (const float*)d_in[0];
    const float* boxes    = (const float*)d_in[1];
    const int*   pidx     = (const int*)d_in[2];
    const float* conv1_w  = (const float*)d_in[3];
    const float* bn1_g    = (const float*)d_in[4];
    const float* bn1_b    = (const float*)d_in[5];
    const float* bn1_m    = (const float*)d_in[6];
    const float* bn1_v    = (const float*)d_in[7];
    const float* conv2_w  = (const float*)d_in[8];
    const float* bn2_g    = (const float*)d_in[9];
    const float* bn2_b    = (const float*)d_in[10];
    const float* bn2_m    = (const float*)d_in[11];
    const float* bn2_v    = (const float*)d_in[12];
    const float* conv1d_w = (const float*)d_in[13];
    const float* conv1d_b = (const float*)d_in[14];
    const float* fc1_w    = (const float*)d_in[15];
    const float* fc1_b    = (const float*)d_in[16];
    const float* fc2_w    = (const float*)d_in[17];
    const float* fc2_b    = (const float*)d_in[18];
    float* out = (float*)d_out;

    char* ws = (char*)d_ws;
    size_t off = 0;
    auto alloc = [&](size_t bytes) -> void* {
        void* p = ws + off;
        off = (off + bytes + 255) & ~(size_t)255;
        return p;
    };
    bf16* apad1 = (bf16*)alloc((size_t)1088 * 25 * 1024 * 2);   // 55.7 MB
    bf16* wb1   = (bf16*)alloc((size_t)512 * 9216 * 2);
    bf16* wb2   = (bf16*)alloc((size_t)256 * 4608 * 2);
    bf16* wb1d  = (bf16*)alloc((size_t)2304 * 6912 * 2);
    bf16* fc1t  = (bf16*)alloc((size_t)1024 * 2304 * 2);
    bf16* apad2 = (bf16*)alloc((size_t)1088 * 25 * 512 * 2);    // 27.9 MB
    float* feat = (float*)alloc((size_t)1088 * 2304 * 4);       // 10 MB
    bf16* bpad  = (bf16*)alloc((size_t)20 * 66 * 2304 * 2);
    bf16* xbuf  = (bf16*)alloc((size_t)64 * 20 * 2304 * 2);
    bf16* hbuf  = (bf16*)alloc((size_t)1024 * 1024 * 2);
    float* s1   = (float*)alloc(512 * 4);
    float* t1   = (float*)alloc(512 * 4);
    float* s2   = (float*)alloc(256 * 4);
    float* t2   = (float*)alloc(256 * 4);
    int* rb1    = (int*)alloc(9856 * 4);
    int* rb2    = (int*)alloc(9856 * 4);
    int* rb1d   = (int*)alloc(1280 * 4);
    int* rbfc   = (int*)alloc(1024 * 4);

    // zero padded activation buffers (borders must be 0)
    hipMemsetAsync(apad1, 0, (size_t)1088 * 25 * 1024 * 2, stream);
    hipMemsetAsync(apad2, 0, (size_t)1088 * 25 * 512 * 2, stream);
    hipMemsetAsync(bpad, 0, (size_t)20 * 66 * 2304 * 2, stream);

    // weight prep
    repack_w<<<(512 * 1024 * 9 + 255) / 256, 256, 0, stream>>>(conv1_w, wb1, 512, 1024, 9);
    repack_w<<<(256 * 512 * 9 + 255) / 256, 256, 0, stream>>>(conv2_w, wb2, 256, 512, 9);
    repack_w<<<(2304 * 2304 * 3 + 255) / 256, 256, 0, stream>>>(conv1d_w, wb1d, 2304, 2304, 3);
    transpose_fc1<<<(1024 * 2304 + 255) / 256, 256, 0, stream>>>(fc1_w, fc1t);
    bn_fold<<<2, 256, 0, stream>>>(bn1_g, bn1_b, bn1_m, bn1_v, s1, t1, 512);
    bn_fold<<<1, 256, 0, stream>>>(bn2_g, bn2_b, bn2_m, bn2_v, s2, t2, 256);
    setup_rowbase<<<(9856 + 255) / 256, 256, 0, stream>>>(rb1, rb2, rb1d, rbfc, pidx);

    // roi_align for all 1088 boxes
    roi_kernel<<<dim3(1088, 4), 256, 0, stream>>>(fmap, boxes, apad1);

    // conv1: M=9792 N=512 K=9216
    gemm_k<0><<<dim3(8, 77), 256, 0, stream>>>(apad1, rb1, wb1, apad2, s1, t1);
    // conv2: M=9792 N=256 K=4608
    gemm_k<1><<<dim3(4, 77), 256, 0, stream>>>(apad2, rb2, wb2, feat, s2, t2);
    // assemble behavior (padded over t)
    assemble<<<dim3(64, 20), 256, 0, stream>>>(feat, pidx, bpad);
    // conv1d: M=1280 N=2304 K=6912
    gemm_k<2><<<dim3(36, 10), 256, 0, stream>>>(bpad, rb1d, wb1d, xbuf, conv1d_b, nullptr);
    // fc1 (+person gather via rowbase): M=1024 N=1024 K=2304
    gemm_k<3><<<dim3(16, 8), 256, 0, stream>>>(xbuf, rbfc, fc1t, hbuf, fc1_b, nullptr);
    // fc2
    fc2_kernel<<<(1024 * 30 + 255) / 256, 256, 0, stream>>>(hbuf, fc2_w, fc2_b, out);
    (void)in_sizes; (void)n_in; (void)out_size; (void)ws_size;
}

// Round 2
// 1020.148 us; speedup vs baseline: 1.2552x; 1.2552x over previous
//
#include <hip/hip_runtime.h>
#include <hip/hip_bf16.h>
#include <cstdint>
#include <cstddef>

typedef __bf16 bf16;
typedef __bf16 bf16x8 __attribute__((ext_vector_type(8)));
typedef float f32x4 __attribute__((ext_vector_type(4)));

// ---------------- weight repack: w[OC][IC][NT] -> out[OC][NT*IC] bf16 (k = tap*IC + ic)
__global__ void __launch_bounds__(256) repack_w(const float* __restrict__ w, bf16* __restrict__ out,
                                                int OC, int IC, int NT) {
    int idx = blockIdx.x * 256 + threadIdx.x;
    int total = OC * IC * NT;
    if (idx >= total) return;
    int oc = idx / (NT * IC);
    int rem = idx - oc * NT * IC;
    int tap = rem / IC;
    int ic  = rem - tap * IC;
    out[idx] = (bf16)w[((size_t)oc * IC + ic) * NT + tap];
}

// ---------------- fc1_w [2304][1024] -> fc1t [1024][2304] bf16
__global__ void __launch_bounds__(256) transpose_fc1(const float* __restrict__ w, bf16* __restrict__ out) {
    int idx = blockIdx.x * 256 + threadIdx.x;
    if (idx >= 1024 * 2304) return;
    int o = idx / 2304;
    int i = idx - o * 2304;
    out[idx] = (bf16)w[(size_t)i * 1024 + o];
}

// ---------------- BN fold: s = g*rsqrt(v+eps), t = b - m*s
__global__ void __launch_bounds__(256) bn_fold(const float* __restrict__ g, const float* __restrict__ b,
                                               const float* __restrict__ m, const float* __restrict__ v,
                                               float* __restrict__ s, float* __restrict__ t, int n) {
    int i = blockIdx.x * 256 + threadIdx.x;
    if (i >= n) return;
    float sc = g[i] * rsqrtf(v[i] + 1e-5f);
    s[i] = sc;
    t[i] = b[i] - m[i] * sc;
}

// ---------------- rowbase arrays for the 4 GEMMs
__global__ void __launch_bounds__(256) setup_rowbase(int* __restrict__ rb1, int* __restrict__ rb2,
                                                     int* __restrict__ rb1d, int* __restrict__ rbfc,
                                                     const int* __restrict__ pidx) {
    int m = blockIdx.x * 256 + threadIdx.x;
    if (m < 9856) {                       // conv1/conv2: M=9792 padded to 77*128
        int mm = m < 9792 ? m : 0;
        int img = mm / 9, pos = mm - img * 9;
        int base = img * 25 + (pos / 3) * 5 + (pos % 3);   // padded 5x5, tap (0,0) origin
        rb1[m] = base * 1024;
        rb2[m] = base * 512;
    }
    if (m < 1280) {                       // conv1d rows: m = p*64 + t
        int p = m >> 6, t = m & 63;
        rb1d[m] = (p * 66 + t) * 2304;
    }
    if (m < 1024) {                       // fc1 rows: m = b*16 + n_, gather person_idx
        int b = m >> 4;
        rbfc[m] = (b * 20 + pidx[m]) * 2304;
    }
}

// ---------------- fmap [64][1024][196] f32 -> fml [64][196][1024] bf16 (LDS tile transpose)
__global__ void __launch_bounds__(256) transpose_fmap(const float* __restrict__ fmap, bf16* __restrict__ fml) {
    __shared__ float t[32][33];
    int img = blockIdx.z;
    int hwT = blockIdx.x * 32;   // 7 tiles (196)
    int cT  = blockIdx.y * 32;   // 32 tiles (1024)
    int tx = threadIdx.x, ty = threadIdx.y;   // 32 x 8
    #pragma unroll
    for (int j = 0; j < 4; j++) {
        int c = cT + ty + j * 8;
        int hw = hwT + tx;
        if (hw < 196)
            t[ty + j * 8][tx] = fmap[((size_t)img * 1024 + c) * 196 + hw];
    }
    __syncthreads();
    #pragma unroll
    for (int j = 0; j < 4; j++) {
        int hw = hwT + ty + j * 8;
        int c = cT + tx;
        if (hw < 196)
            fml[((size_t)img * 196 + hw) * 1024 + c] = (bf16)t[tx][ty + j * 8];
    }
}

// ---------------- roi_align (channels-last) -> apad1[1088][5][5][1024] bf16 interior
__global__ void __launch_bounds__(128) roi_kernel2(const bf16* __restrict__ fml, const float* __restrict__ boxes,
                                                   bf16* __restrict__ apad) {
    int box = blockIdx.x;
    int tid = threadIdx.x;        // 128 lanes, lane owns 8 channels
    float x1, y1, x2, y2;
    int img;
    if (box < 64) { img = box; x1 = 0.f; y1 = 0.f; x2 = 14.f; y2 = 14.f; }
    else {
        int ib = box - 64;
        img = ib >> 4;
        const float* bb = boxes + (size_t)ib * 4;
        x1 = bb[0]; y1 = bb[1]; x2 = bb[2]; y2 = bb[3];
    }
    float rw = fmaxf(x2 - x1, 1.f), rh = fmaxf(y2 - y1, 1.f);
    __shared__ float swy[6], swx[6];
    __shared__ int sy0[6], sx0[6];
    if (tid < 6) {
        int i = tid;
        float pos = ((float)i + 0.5f) * 0.5f;
        float yv = fminf(fmaxf(y1 + pos * (rh * (1.f / 3.f)), 0.f), 13.f);
        float y0 = floorf(yv);
        sy0[i] = (int)y0; swy[i] = yv - y0;
        float xv = fminf(fmaxf(x1 + pos * (rw * (1.f / 3.f)), 0.f), 13.f);
        float x0 = floorf(xv);
        sx0[i] = (int)x0; swx[i] = xv - x0;
    }
    __syncthreads();
    const bf16* base = fml + (size_t)img * 196 * 1024 + tid * 8;
    #pragma unroll
    for (int oy = 0; oy < 3; oy++) {
        #pragma unroll
        for (int ox = 0; ox < 3; ox++) {
            float acc[8];
            #pragma unroll
            for (int e = 0; e < 8; e++) acc[e] = 0.f;
            #pragma unroll
            for (int dy = 0; dy < 2; dy++) {
                int sy = 2 * oy + dy;
                int y0 = sy0[sy]; float wy = swy[sy];
                int y1i = min(y0 + 1, 13);
                #pragma unroll
                for (int dx = 0; dx < 2; dx++) {
                    int sx = 2 * ox + dx;
                    int x0 = sx0[sx]; float wx = swx[sx];
                    int x1i = min(x0 + 1, 13);
                    bf16x8 f00 = *(const bf16x8*)(base + (size_t)(y0 * 14 + x0) * 1024);
                    bf16x8 f01 = *(const bf16x8*)(base + (size_t)(y0 * 14 + x1i) * 1024);
                    bf16x8 f10 = *(const bf16x8*)(base + (size_t)(y1i * 14 + x0) * 1024);
                    bf16x8 f11 = *(const bf16x8*)(base + (size_t)(y1i * 14 + x1i) * 1024);
                    float w00 = (1.f - wy) * (1.f - wx), w01 = (1.f - wy) * wx;
                    float w10 = wy * (1.f - wx),         w11 = wy * wx;
                    #pragma unroll
                    for (int e = 0; e < 8; e++)
                        acc[e] += w00 * (float)f00[e] + w01 * (float)f01[e]
                                + w10 * (float)f10[e] + w11 * (float)f11[e];
                }
            }
            bf16x8 o;
            #pragma unroll
            for (int e = 0; e < 8; e++) o[e] = (bf16)(acc[e] * 0.25f);
            *(bf16x8*)(apad + ((size_t)box * 25 + (oy + 1) * 5 + (ox + 1)) * 1024 + tid * 8) = o;
        }
    }
}

// ---------------- behavior assembly: bpad[p][t+1][f] = g_feat[t] + sum_{n: idx==p} i_feat[t,n]
__global__ void __launch_bounds__(256) assemble(const float* __restrict__ feat, const int* __restrict__ pidx,
                                                bf16* __restrict__ bpad) {
    int b = blockIdx.x;   // 0..63 (time index)
    int p = blockIdx.y;   // 0..19
    __shared__ int idxs[16];
    if (threadIdx.x < 16) idxs[threadIdx.x] = pidx[b * 16 + threadIdx.x];
    __syncthreads();
    const float* g = feat + (size_t)b * 2304;
    for (int f = threadIdx.x; f < 2304; f += 256) {
        float v = g[f];
        #pragma unroll
        for (int n = 0; n < 16; n++)
            if (idxs[n] == p) v += feat[(size_t)(64 + b * 16 + n) * 2304 + f];
        bpad[((size_t)p * 66 + (b + 1)) * 2304 + f] = (bf16)v;
    }
}

// ---------------- unified implicit-GEMM MFMA kernel
// C[M][N] = sum_k A[rowbase[m] + posOff(k/Cin)*Cin + k%Cin] * B[n*K + k]
// BM=128, BN=64, BK=64; 4 waves, each wave: 32 rows x 64 cols (2x4 16x16x32 tiles)
template <int MODE>
__global__ void __launch_bounds__(256) gemm_k(const bf16* __restrict__ A, const int* __restrict__ rowbase,
                                              const bf16* __restrict__ Bw, void* __restrict__ outp,
                                              const float* __restrict__ c0, const float* __restrict__ c1) {
    constexpr int K   = MODE == 0 ? 9216 : MODE == 1 ? 4608 : MODE == 2 ? 6912 : 2304;
    constexpr int Cin = MODE == 0 ? 1024 : MODE == 1 ? 512  : 2304;
    constexpr int M   = MODE <= 1 ? 9792 : MODE == 2 ? 1280 : 1024;
    constexpr bool C3 = (MODE <= 1);
    constexpr bool MPAD = (M % 128) != 0;

    const int bm = blockIdx.y * 128;
    const int bn = blockIdx.x * 64;
    const int tid = threadIdx.x;
    const int lane = tid & 63, wave = tid >> 6;
    const int q = lane >> 4, ln16 = lane & 15;

    __shared__ __align__(16) bf16 As[128 * 72];
    __shared__ __align__(16) bf16 Bs[64 * 72];
    __shared__ int rb[128];

    if (tid < 128) rb[tid] = rowbase[bm + tid];

    f32x4 acc[2][4];
    #pragma unroll
    for (int mt = 0; mt < 2; mt++)
        #pragma unroll
        for (int nt = 0; nt < 4; nt++)
            acc[mt][nt] = (f32x4){0.f, 0.f, 0.f, 0.f};

    for (int kt = 0; kt < K / 64; kt++) {
        const int k0 = kt * 64;
        const int tap = k0 / Cin;                 // constexpr divisor -> cheap
        const int inner = k0 - tap * Cin;
        const int poff = C3 ? ((tap / 3) * 5 + (tap % 3)) : tap;
        const int aoff = poff * Cin + inner;

        __syncthreads();   // protect LDS (and rb on iter 0) before overwrite
        #pragma unroll
        for (int u = 0; u < 4; u++) {            // stage A: 128 rows x 8 chunks
            int id = tid + u * 256;
            int row = id >> 3, c = id & 7;
            const bf16* src = A + (size_t)(rb[row] + aoff + c * 8);
            *(bf16x8*)(As + row * 72 + c * 8) = *(const bf16x8*)src;
        }
        #pragma unroll
        for (int u = 0; u < 2; u++) {            // stage B: 64 rows x 8 chunks
            int id = tid + u * 256;
            int row = id >> 3, c = id & 7;
            const bf16* src = Bw + (size_t)(bn + row) * K + k0 + c * 8;
            *(bf16x8*)(Bs + row * 72 + c * 8) = *(const bf16x8*)src;
        }
        __syncthreads();

        #pragma unroll
        for (int s = 0; s < 2; s++) {
            bf16x8 af[2], bfr[4];
            #pragma unroll
            for (int mt = 0; mt < 2; mt++)
                af[mt] = *(const bf16x8*)(As + (wave * 32 + mt * 16 + ln16) * 72 + s * 32 + q * 8);
            #pragma unroll
            for (int nt = 0; nt < 4; nt++)
                bfr[nt] = *(const bf16x8*)(Bs + (nt * 16 + ln16) * 72 + s * 32 + q * 8);
            #pragma unroll
            for (int mt = 0; mt < 2; mt++)
                #pragma unroll
                for (int nt = 0; nt < 4; nt++)
                    acc[mt][nt] = __builtin_amdgcn_mfma_f32_16x16x32_bf16(af[mt], bfr[nt], acc[mt][nt], 0, 0, 0);
        }
    }

    // epilogue: C/D layout col=lane&15, row=quad*4+reg
    #pragma unroll
    for (int mt = 0; mt < 2; mt++) {
        int gmBase = bm + wave * 32 + mt * 16 + q * 4;
        #pragma unroll
        for (int r = 0; r < 4; r++) {
            int gm = gmBase + r;
            if (MPAD && gm >= M) continue;
            #pragma unroll
            for (int nt = 0; nt < 4; nt++) {
                int gn = bn + nt * 16 + ln16;
                float v = acc[mt][nt][r];
                if constexpr (MODE == 0) {        // conv1: BN+leaky -> apad2 bf16 interior
                    v = v * c0[gn] + c1[gn];
                    v = v > 0.f ? v : 0.1f * v;
                    int img = gm / 9, pos = gm - img * 9;
                    ((bf16*)outp)[(size_t)(img * 25 + (pos / 3 + 1) * 5 + (pos % 3 + 1)) * 512 + gn] = (bf16)v;
                } else if constexpr (MODE == 1) { // conv2: BN+leaky -> feat fp32 [img][oc*9+pos]
                    v = v * c0[gn] + c1[gn];
                    v = v > 0.f ? v : 0.1f * v;
                    int img = gm / 9, pos = gm - img * 9;
                    ((float*)outp)[(size_t)img * 2304 + gn * 9 + pos] = v;
                } else if constexpr (MODE == 2) { // conv1d: +bias -> xbuf[t][p][oc] bf16
                    v += c0[gn];
                    int p = gm >> 6, t = gm & 63;
                    ((bf16*)outp)[(size_t)(t * 20 + p) * 2304 + gn] = (bf16)v;
                } else {                          // fc1: +bias, relu -> hbuf bf16
                    v = fmaxf(v + c0[gn], 0.f);
                    ((bf16*)outp)[(size_t)gm * 1024 + gn] = (bf16)v;
                }
            }
        }
    }
}

// ---------------- fc2: out[1024][30] = h[1024][1024] @ w2[1024][30] + b2
__global__ void __launch_bounds__(256) fc2_kernel(const bf16* __restrict__ h, const float* __restrict__ w2,
                                                  const float* __restrict__ b2, float* __restrict__ out) {
    int idx = blockIdx.x * 256 + threadIdx.x;
    if (idx >= 1024 * 30) return;
    int m = idx / 30, n = idx - m * 30;
    const bf16* hr = h + (size_t)m * 1024;
    float a0 = 0.f, a1 = 0.f, a2 = 0.f, a3 = 0.f;
    for (int k = 0; k < 1024; k += 4) {
        a0 += (float)hr[k]     * w2[(size_t)k * 30 + n];
        a1 += (float)hr[k + 1] * w2[(size_t)(k + 1) * 30 + n];
        a2 += (float)hr[k + 2] * w2[(size_t)(k + 2) * 30 + n];
        a3 += (float)hr[k + 3] * w2[(size_t)(k + 3) * 30 + n];
    }
    out[idx] = a0 + a1 + a2 + a3 + b2[n];
}

extern "C" void kernel_launch(void* const* d_in, const int* in_sizes, int n_in,
                              void* d_out, int out_size, void* d_ws, size_t ws_size,
                              hipStream_t stream) {
    const float* fmap     = (const float*)d_in[0];
    const float* boxes    = (const float*)d_in[1];
    const int*   pidx     = (const int*)d_in[2];
    const float* conv1_w  = (const float*)d_in[3];
    const float* bn1_g    = (const float*)d_in[4];
    const float* bn1_b    = (const float*)d_in[5];
    const float* bn1_m    = (const float*)d_in[6];
    const float* bn1_v    = (const float*)d_in[7];
    const float* conv2_w  = (const float*)d_in[8];
    const float* bn2_g    = (const float*)d_in[9];
    const float* bn2_b    = (const float*)d_in[10];
    const float* bn2_m    = (const float*)d_in[11];
    const float* bn2_v    = (const float*)d_in[12];
    const float* conv1d_w = (const float*)d_in[13];
    const float* conv1d_b = (const float*)d_in[14];
    const float* fc1_w    = (const float*)d_in[15];
    const float* fc1_b    = (const float*)d_in[16];
    const float* fc2_w    = (const float*)d_in[17];
    const float* fc2_b    = (const float*)d_in[18];
    float* out = (float*)d_out;

    char* ws = (char*)d_ws;
    size_t off = 0;
    auto alloc = [&](size_t bytes) -> void* {
        void* p = ws + off;
        off = (off + bytes + 255) & ~(size_t)255;
        return p;
    };
    bf16* apad1 = (bf16*)alloc((size_t)1088 * 25 * 1024 * 2);   // 55.7 MB
    bf16* wb1   = (bf16*)alloc((size_t)512 * 9216 * 2);
    bf16* wb2   = (bf16*)alloc((size_t)256 * 4608 * 2);
    bf16* wb1d  = (bf16*)alloc((size_t)2304 * 6912 * 2);
    bf16* fc1t  = (bf16*)alloc((size_t)1024 * 2304 * 2);
    bf16* apad2 = (bf16*)alloc((size_t)1088 * 25 * 512 * 2);    // 27.9 MB
    float* feat = (float*)alloc((size_t)1088 * 2304 * 4);       // 10 MB
    bf16* bpad  = (bf16*)alloc((size_t)20 * 66 * 2304 * 2);
    bf16* xbuf  = (bf16*)alloc((size_t)64 * 20 * 2304 * 2);
    bf16* hbuf  = (bf16*)alloc((size_t)1024 * 1024 * 2);
    bf16* fml   = (bf16*)alloc((size_t)64 * 196 * 1024 * 2);    // 25.7 MB channels-last fmap
    float* s1   = (float*)alloc(512 * 4);
    float* t1   = (float*)alloc(512 * 4);
    float* s2   = (float*)alloc(256 * 4);
    float* t2   = (float*)alloc(256 * 4);
    int* rb1    = (int*)alloc(9856 * 4);
    int* rb2    = (int*)alloc(9856 * 4);
    int* rb1d   = (int*)alloc(1280 * 4);
    int* rbfc   = (int*)alloc(1024 * 4);

    // zero padded activation buffers (borders must be 0)
    hipMemsetAsync(apad1, 0, (size_t)1088 * 25 * 1024 * 2, stream);
    hipMemsetAsync(apad2, 0, (size_t)1088 * 25 * 512 * 2, stream);
    hipMemsetAsync(bpad, 0, (size_t)20 * 66 * 2304 * 2, stream);

    // weight prep
    repack_w<<<(512 * 1024 * 9 + 255) / 256, 256, 0, stream>>>(conv1_w, wb1, 512, 1024, 9);
    repack_w<<<(256 * 512 * 9 + 255) / 256, 256, 0, stream>>>(conv2_w, wb2, 256, 512, 9);
    repack_w<<<(2304 * 2304 * 3 + 255) / 256, 256, 0, stream>>>(conv1d_w, wb1d, 2304, 2304, 3);
    transpose_fc1<<<(1024 * 2304 + 255) / 256, 256, 0, stream>>>(fc1_w, fc1t);
    bn_fold<<<2, 256, 0, stream>>>(bn1_g, bn1_b, bn1_m, bn1_v, s1, t1, 512);
    bn_fold<<<1, 256, 0, stream>>>(bn2_g, bn2_b, bn2_m, bn2_v, s2, t2, 256);
    setup_rowbase<<<(9856 + 255) / 256, 256, 0, stream>>>(rb1, rb2, rb1d, rbfc, pidx);

    // channels-last bf16 fmap, then roi_align for all 1088 boxes
    transpose_fmap<<<dim3(7, 32, 64), dim3(32, 8), 0, stream>>>(fmap, fml);
    roi_kernel2<<<1088, 128, 0, stream>>>(fml, boxes, apad1);

    // conv1: M=9792 N=512 K=9216
    gemm_k<0><<<dim3(8, 77), 256, 0, stream>>>(apad1, rb1, wb1, apad2, s1, t1);
    // conv2: M=9792 N=256 K=4608
    gemm_k<1><<<dim3(4, 77), 256, 0, stream>>>(apad2, rb2, wb2, feat, s2, t2);
    // assemble behavior (padded over t)
    assemble<<<dim3(64, 20), 256, 0, stream>>>(feat, pidx, bpad);
    // conv1d: M=1280 N=2304 K=6912
    gemm_k<2><<<dim3(36, 10), 256, 0, stream>>>(bpad, rb1d, wb1d, xbuf, conv1d_b, nullptr);
    // fc1 (+person gather via rowbase): M=1024 N=1024 K=2304
    gemm_k<3><<<dim3(16, 8), 256, 0, stream>>>(xbuf, rbfc, fc1t, hbuf, fc1_b, nullptr);
    // fc2
    fc2_kernel<<<(1024 * 30 + 255) / 256, 256, 0, stream>>>(hbuf, fc2_w, fc2_b, out);
    (void)in_sizes; (void)n_in; (void)out_size; (void)ws_size;
}

// Round 3
// 743.880 us; speedup vs baseline: 1.7214x; 1.3714x over previous
//
#include <hip/hip_runtime.h>
#include <hip/hip_bf16.h>
#include <cstdint>
#include <cstddef>

typedef __bf16 bf16;
typedef __bf16 bf16x8 __attribute__((ext_vector_type(8)));
typedef float f32x4 __attribute__((ext_vector_type(4)));

// ---------------- weight repack: w[OC][IC][NT] -> out[OC][NT*IC] bf16 (k = tap*IC + ic)
__global__ void __launch_bounds__(256) repack_w(const float* __restrict__ w, bf16* __restrict__ out,
                                                int OC, int IC, int NT) {
    int idx = blockIdx.x * 256 + threadIdx.x;
    int total = OC * IC * NT;
    if (idx >= total) return;
    int oc = idx / (NT * IC);
    int rem = idx - oc * NT * IC;
    int tap = rem / IC;
    int ic  = rem - tap * IC;
    out[idx] = (bf16)w[((size_t)oc * IC + ic) * NT + tap];
}

// ---------------- fc1_w [2304][1024] -> fc1t [1024][2304] bf16
__global__ void __launch_bounds__(256) transpose_fc1(const float* __restrict__ w, bf16* __restrict__ out) {
    int idx = blockIdx.x * 256 + threadIdx.x;
    if (idx >= 1024 * 2304) return;
    int o = idx / 2304;
    int i = idx - o * 2304;
    out[idx] = (bf16)w[(size_t)i * 1024 + o];
}

// ---------------- BN fold: s = g*rsqrt(v+eps), t = b - m*s
__global__ void __launch_bounds__(256) bn_fold(const float* __restrict__ g, const float* __restrict__ b,
                                               const float* __restrict__ m, const float* __restrict__ v,
                                               float* __restrict__ s, float* __restrict__ t, int n) {
    int i = blockIdx.x * 256 + threadIdx.x;
    if (i >= n) return;
    float sc = g[i] * rsqrtf(v[i] + 1e-5f);
    s[i] = sc;
    t[i] = b[i] - m[i] * sc;
}

// ---------------- rowbase arrays for the 4 GEMMs
__global__ void __launch_bounds__(256) setup_rowbase(int* __restrict__ rb1, int* __restrict__ rb2,
                                                     int* __restrict__ rb1d, int* __restrict__ rbfc,
                                                     const int* __restrict__ pidx) {
    int m = blockIdx.x * 256 + threadIdx.x;
    if (m < 9856) {                       // conv1/conv2: M=9792 padded to 77*128
        int mm = m < 9792 ? m : 0;
        int img = mm / 9, pos = mm - img * 9;
        int base = img * 25 + (pos / 3) * 5 + (pos % 3);   // padded 5x5, tap (0,0) origin
        rb1[m] = base * 1024;
        rb2[m] = base * 512;
    }
    if (m < 1280) {                       // conv1d rows: m = p*64 + t
        int p = m >> 6, t = m & 63;
        rb1d[m] = (p * 66 + t) * 2304;
    }
    if (m < 1024) {                       // fc1 rows: m = b*16 + n_, gather person_idx
        int b = m >> 4;
        rbfc[m] = (b * 20 + pidx[m]) * 2304;
    }
}

// ---------------- fmap [64][1024][196] f32 -> fml [64][196][1024] bf16 (LDS tile transpose)
__global__ void __launch_bounds__(256) transpose_fmap(const float* __restrict__ fmap, bf16* __restrict__ fml) {
    __shared__ float t[32][33];
    int img = blockIdx.z;
    int hwT = blockIdx.x * 32;   // 7 tiles (196)
    int cT  = blockIdx.y * 32;   // 32 tiles (1024)
    int tx = threadIdx.x, ty = threadIdx.y;   // 32 x 8
    #pragma unroll
    for (int j = 0; j < 4; j++) {
        int c = cT + ty + j * 8;
        int hw = hwT + tx;
        if (hw < 196)
            t[ty + j * 8][tx] = fmap[((size_t)img * 1024 + c) * 196 + hw];
    }
    __syncthreads();
    #pragma unroll
    for (int j = 0; j < 4; j++) {
        int hw = hwT + ty + j * 8;
        int c = cT + tx;
        if (hw < 196)
            fml[((size_t)img * 196 + hw) * 1024 + c] = (bf16)t[tx][ty + j * 8];
    }
}

// ---------------- roi_align (channels-last) -> apad1[1088][5][5][1024] bf16 interior
__global__ void __launch_bounds__(128) roi_kernel2(const bf16* __restrict__ fml, const float* __restrict__ boxes,
                                                   bf16* __restrict__ apad) {
    int box = blockIdx.x;
    int tid = threadIdx.x;        // 128 lanes, lane owns 8 channels
    float x1, y1, x2, y2;
    int img;
    if (box < 64) { img = box; x1 = 0.f; y1 = 0.f; x2 = 14.f; y2 = 14.f; }
    else {
        int ib = box - 64;
        img = ib >> 4;
        const float* bb = boxes + (size_t)ib * 4;
        x1 = bb[0]; y1 = bb[1]; x2 = bb[2]; y2 = bb[3];
    }
    float rw = fmaxf(x2 - x1, 1.f), rh = fmaxf(y2 - y1, 1.f);
    __shared__ float swy[6], swx[6];
    __shared__ int sy0[6], sx0[6];
    if (tid < 6) {
        int i = tid;
        float pos = ((float)i + 0.5f) * 0.5f;
        float yv = fminf(fmaxf(y1 + pos * (rh * (1.f / 3.f)), 0.f), 13.f);
        float y0 = floorf(yv);
        sy0[i] = (int)y0; swy[i] = yv - y0;
        float xv = fminf(fmaxf(x1 + pos * (rw * (1.f / 3.f)), 0.f), 13.f);
        float x0 = floorf(xv);
        sx0[i] = (int)x0; swx[i] = xv - x0;
    }
    __syncthreads();
    const bf16* base = fml + (size_t)img * 196 * 1024 + tid * 8;
    #pragma unroll
    for (int oy = 0; oy < 3; oy++) {
        #pragma unroll
        for (int ox = 0; ox < 3; ox++) {
            float acc[8];
            #pragma unroll
            for (int e = 0; e < 8; e++) acc[e] = 0.f;
            #pragma unroll
            for (int dy = 0; dy < 2; dy++) {
                int sy = 2 * oy + dy;
                int y0 = sy0[sy]; float wy = swy[sy];
                int y1i = min(y0 + 1, 13);
                #pragma unroll
                for (int dx = 0; dx < 2; dx++) {
                    int sx = 2 * ox + dx;
                    int x0 = sx0[sx]; float wx = swx[sx];
                    int x1i = min(x0 + 1, 13);
                    bf16x8 f00 = *(const bf16x8*)(base + (size_t)(y0 * 14 + x0) * 1024);
                    bf16x8 f01 = *(const bf16x8*)(base + (size_t)(y0 * 14 + x1i) * 1024);
                    bf16x8 f10 = *(const bf16x8*)(base + (size_t)(y1i * 14 + x0) * 1024);
                    bf16x8 f11 = *(const bf16x8*)(base + (size_t)(y1i * 14 + x1i) * 1024);
                    float w00 = (1.f - wy) * (1.f - wx), w01 = (1.f - wy) * wx;
                    float w10 = wy * (1.f - wx),         w11 = wy * wx;
                    #pragma unroll
                    for (int e = 0; e < 8; e++)
                        acc[e] += w00 * (float)f00[e] + w01 * (float)f01[e]
                                + w10 * (float)f10[e] + w11 * (float)f11[e];
                }
            }
            bf16x8 o;
            #pragma unroll
            for (int e = 0; e < 8; e++) o[e] = (bf16)(acc[e] * 0.25f);
            *(bf16x8*)(apad + ((size_t)box * 25 + (oy + 1) * 5 + (ox + 1)) * 1024 + tid * 8) = o;
        }
    }
}

// ---------------- behavior assembly: bpad[p][t+1][f] = g_feat[t] + sum_{n: idx==p} i_feat[t,n]
__global__ void __launch_bounds__(256) assemble(const float* __restrict__ feat, const int* __restrict__ pidx,
                                                bf16* __restrict__ bpad) {
    int b = blockIdx.x;   // 0..63 (time index)
    int p = blockIdx.y;   // 0..19
    __shared__ int idxs[16];
    if (threadIdx.x < 16) idxs[threadIdx.x] = pidx[b * 16 + threadIdx.x];
    __syncthreads();
    const float* g = feat + (size_t)b * 2304;
    for (int f = threadIdx.x; f < 2304; f += 256) {
        float v = g[f];
        #pragma unroll
        for (int n = 0; n < 16; n++)
            if (idxs[n] == p) v += feat[(size_t)(64 + b * 16 + n) * 2304 + f];
        bpad[((size_t)p * 66 + (b + 1)) * 2304 + f] = (bf16)v;
    }
}

// ---------------- unified implicit-GEMM MFMA kernel (XOR-swizzled LDS, optional split-K)
// C[M][N] = sum_k A[rowbase[m] + posOff(k/Cin)*Cin + k%Cin] * B[n*K + k]
// BM=128, BN=64, BK=64; 4 waves, each wave: 32 rows x 64 cols (2x4 16x16x32 tiles)
// LDS layout: row stride 64 elems, chunk c of row r stored at column (c ^ (r&7))*8
// -> bank-conflict-free b128 reads and writes (8-way -> floor).
template <int MODE, int NSPLIT>
__global__ void __launch_bounds__(256) gemm_k(const bf16* __restrict__ A, const int* __restrict__ rowbase,
                                              const bf16* __restrict__ Bw, void* __restrict__ outp,
                                              const float* __restrict__ c0, const float* __restrict__ c1) {
    constexpr int K   = MODE == 0 ? 9216 : MODE == 1 ? 4608 : MODE == 2 ? 6912 : 2304;
    constexpr int N   = MODE == 0 ? 512  : MODE == 1 ? 256  : MODE == 2 ? 2304 : 1024;
    constexpr int Cin = MODE == 0 ? 1024 : MODE == 1 ? 512  : 2304;
    constexpr int M   = MODE <= 1 ? 9792 : MODE == 2 ? 1280 : 1024;
    constexpr bool C3 = (MODE <= 1);
    constexpr bool MPAD = (M % 128) != 0;
    constexpr int KTS = (K / 64) / NSPLIT;     // kt iterations per slice

    const int bm = blockIdx.y * 128;
    const int bn = blockIdx.x * 64;
    const int z  = blockIdx.z;
    const int tid = threadIdx.x;
    const int lane = tid & 63, wave = tid >> 6;
    const int q = lane >> 4, ln16 = lane & 15;

    __shared__ __align__(16) bf16 As[128 * 64];
    __shared__ __align__(16) bf16 Bs[64 * 64];
    __shared__ int rb[128];

    if (tid < 128) rb[tid] = rowbase[bm + tid];

    f32x4 acc[2][4];
    #pragma unroll
    for (int mt = 0; mt < 2; mt++)
        #pragma unroll
        for (int nt = 0; nt < 4; nt++)
            acc[mt][nt] = (f32x4){0.f, 0.f, 0.f, 0.f};

    for (int kt = z * KTS; kt < z * KTS + KTS; kt++) {
        const int k0 = kt * 64;
        const int tap = k0 / Cin;                 // constexpr divisor -> cheap
        const int inner = k0 - tap * Cin;
        const int poff = C3 ? ((tap / 3) * 5 + (tap % 3)) : tap;
        const int aoff = poff * Cin + inner;

        __syncthreads();   // protect LDS (and rb on iter 0) before overwrite
        #pragma unroll
        for (int u = 0; u < 4; u++) {            // stage A: 128 rows x 8 chunks
            int id = tid + u * 256;
            int row = id >> 3, c = id & 7;
            const bf16* src = A + (size_t)(rb[row] + aoff + c * 8);
            *(bf16x8*)(As + row * 64 + ((c ^ (row & 7)) << 3)) = *(const bf16x8*)src;
        }
        #pragma unroll
        for (int u = 0; u < 2; u++) {            // stage B: 64 rows x 8 chunks
            int id = tid + u * 256;
            int row = id >> 3, c = id & 7;
            const bf16* src = Bw + (size_t)(bn + row) * K + k0 + c * 8;
            *(bf16x8*)(Bs + row * 64 + ((c ^ (row & 7)) << 3)) = *(const bf16x8*)src;
        }
        __syncthreads();

        #pragma unroll
        for (int s = 0; s < 2; s++) {
            bf16x8 af[2], bfr[4];
            #pragma unroll
            for (int mt = 0; mt < 2; mt++) {
                int r = wave * 32 + mt * 16 + ln16;
                af[mt] = *(const bf16x8*)(As + r * 64 + (((4 * s + q) ^ (r & 7)) << 3));
            }
            #pragma unroll
            for (int nt = 0; nt < 4; nt++) {
                int r = nt * 16 + ln16;
                bfr[nt] = *(const bf16x8*)(Bs + r * 64 + (((4 * s + q) ^ (r & 7)) << 3));
            }
            #pragma unroll
            for (int mt = 0; mt < 2; mt++)
                #pragma unroll
                for (int nt = 0; nt < 4; nt++)
                    acc[mt][nt] = __builtin_amdgcn_mfma_f32_16x16x32_bf16(af[mt], bfr[nt], acc[mt][nt], 0, 0, 0);
        }
    }

    // epilogue: C/D layout col=lane&15, row=quad*4+reg
    #pragma unroll
    for (int mt = 0; mt < 2; mt++) {
        int gmBase = bm + wave * 32 + mt * 16 + q * 4;
        #pragma unroll
        for (int r = 0; r < 4; r++) {
            int gm = gmBase + r;
            if (MPAD && gm >= M) continue;
            #pragma unroll
            for (int nt = 0; nt < 4; nt++) {
                int gn = bn + nt * 16 + ln16;
                float v = acc[mt][nt][r];
                if constexpr (NSPLIT > 1) {       // raw fp32 partial per slice
                    ((float*)outp)[((size_t)z * M + gm) * N + gn] = v;
                } else if constexpr (MODE == 0) { // conv1: BN+leaky -> apad2 bf16 interior
                    v = v * c0[gn] + c1[gn];
                    v = v > 0.f ? v : 0.1f * v;
                    int img = gm / 9, pos = gm - img * 9;
                    ((bf16*)outp)[(size_t)(img * 25 + (pos / 3 + 1) * 5 + (pos % 3 + 1)) * 512 + gn] = (bf16)v;
                } else if constexpr (MODE == 1) { // conv2: BN+leaky -> feat fp32 [img][oc*9+pos]
                    v = v * c0[gn] + c1[gn];
                    v = v > 0.f ? v : 0.1f * v;
                    int img = gm / 9, pos = gm - img * 9;
                    ((float*)outp)[(size_t)img * 2304 + gn * 9 + pos] = v;
                } else if constexpr (MODE == 2) { // conv1d: +bias -> xbuf[t][p][oc] bf16
                    v += c0[gn];
                    int p = gm >> 6, t = gm & 63;
                    ((bf16*)outp)[(size_t)(t * 20 + p) * 2304 + gn] = (bf16)v;
                } else {                          // fc1: +bias, relu -> hbuf bf16
                    v = fmaxf(v + c0[gn], 0.f);
                    ((bf16*)outp)[(size_t)gm * 1024 + gn] = (bf16)v;
                }
            }
        }
    }
}

// ---------------- split-K reducers
// RMODE 0: conv2 partials -> feat fp32 (BN+leaky, scatter [img][oc*9+pos])
// RMODE 1: conv1d partials -> xbuf bf16 (+bias, [t][p][oc])
// RMODE 2: fc1 partials -> hbuf bf16 (+bias, relu)
template <int RMODE>
__global__ void __launch_bounds__(256) reduce_k(const float* __restrict__ part, void* __restrict__ outp,
                                                const float* __restrict__ c0, const float* __restrict__ c1) {
    constexpr int M = RMODE == 0 ? 9792 : RMODE == 1 ? 1280 : 1024;
    constexpr int N = RMODE == 0 ? 256  : RMODE == 1 ? 2304 : 1024;
    constexpr int S = RMODE == 0 ? 2    : RMODE == 1 ? 6    : 4;
    int idx = blockIdx.x * 256 + threadIdx.x;
    if (idx >= M * N) return;
    int m = idx / N, n = idx - m * N;
    float v = 0.f;
    #pragma unroll
    for (int s = 0; s < S; s++) v += part[(size_t)s * M * N + idx];
    if constexpr (RMODE == 0) {
        v = v * c0[n] + c1[n];
        v = v > 0.f ? v : 0.1f * v;
        int img = m / 9, pos = m - img * 9;
        ((float*)outp)[(size_t)img * 2304 + n * 9 + pos] = v;
    } else if constexpr (RMODE == 1) {
        v += c0[n];
        int p = m >> 6, t = m & 63;
        ((bf16*)outp)[((size_t)t * 20 + p) * 2304 + n] = (bf16)v;
    } else {
        v = fmaxf(v + c0[n], 0.f);
        ((bf16*)outp)[idx] = (bf16)v;
    }
}

// ---------------- fc2: out[1024][30] = h[1024][1024] @ w2[1024][30] + b2
__global__ void __launch_bounds__(256) fc2_kernel(const bf16* __restrict__ h, const float* __restrict__ w2,
                                                  const float* __restrict__ b2, float* __restrict__ out) {
    int idx = blockIdx.x * 256 + threadIdx.x;
    if (idx >= 1024 * 30) return;
    int m = idx / 30, n = idx - m * 30;
    const bf16* hr = h + (size_t)m * 1024;
    float a0 = 0.f, a1 = 0.f, a2 = 0.f, a3 = 0.f;
    for (int k = 0; k < 1024; k += 4) {
        a0 += (float)hr[k]     * w2[(size_t)k * 30 + n];
        a1 += (float)hr[k + 1] * w2[(size_t)(k + 1) * 30 + n];
        a2 += (float)hr[k + 2] * w2[(size_t)(k + 2) * 30 + n];
        a3 += (float)hr[k + 3] * w2[(size_t)(k + 3) * 30 + n];
    }
    out[idx] = a0 + a1 + a2 + a3 + b2[n];
}

extern "C" void kernel_launch(void* const* d_in, const int* in_sizes, int n_in,
                              void* d_out, int out_size, void* d_ws, size_t ws_size,
                              hipStream_t stream) {
    const float* fmap     = (const float*)d_in[0];
    const float* boxes    = (const float*)d_in[1];
    const int*   pidx     = (const int*)d_in[2];
    const float* conv1_w  = (const float*)d_in[3];
    const float* bn1_g    = (const float*)d_in[4];
    const float* bn1_b    = (const float*)d_in[5];
    const float* bn1_m    = (const float*)d_in[6];
    const float* bn1_v    = (const float*)d_in[7];
    const float* conv2_w  = (const float*)d_in[8];
    const float* bn2_g    = (const float*)d_in[9];
    const float* bn2_b    = (const float*)d_in[10];
    const float* bn2_m    = (const float*)d_in[11];
    const float* bn2_v    = (const float*)d_in[12];
    const float* conv1d_w = (const float*)d_in[13];
    const float* conv1d_b = (const float*)d_in[14];
    const float* fc1_w    = (const float*)d_in[15];
    const float* fc1_b    = (const float*)d_in[16];
    const float* fc2_w    = (const float*)d_in[17];
    const float* fc2_b    = (const float*)d_in[18];
    float* out = (float*)d_out;

    char* ws = (char*)d_ws;

    // ---- overlapped arena (phases don't alias live buffers) ----
    // [0, 25.69M)  fml          (live: transpose_fmap .. roi)
    // [25.69M, 81.40M) apad1    (live: roi .. conv1)
    // [81.40M, 90.83M) wb1      (live: repack .. conv1)
    // [90.83M, 93.19M) wb2      (live: repack .. conv2)
    // [93.19M, 121.04M) apad2   (live: conv1 .. conv2)
    // [0, 20.05M)  part2        (live: conv2 .. reduce2)   -- over dead fml
    // [0, 70.78M)  part1d       (live: conv1d .. reduce1d) -- over dead fml+apad1
    // [0, 16.78M)  partfc       (live: fc1 .. reducefc)    -- over dead part1d
    bf16*  fml    = (bf16*)(ws + 0);
    bf16*  apad1  = (bf16*)(ws + 25690112);
    bf16*  wb1    = (bf16*)(ws + 81395712);
    bf16*  wb2    = (bf16*)(ws + 90832896);
    bf16*  apad2  = (bf16*)(ws + 93192192);
    float* part2  = (float*)(ws + 0);
    float* part1d = (float*)(ws + 0);
    float* partfc = (float*)(ws + 0);
    size_t off = 121044992;
    auto alloc = [&](size_t bytes) -> void* {
        void* p = ws + off;
        off = (off + bytes + 255) & ~(size_t)255;
        return p;
    };
    bf16* wb1d  = (bf16*)alloc((size_t)2304 * 6912 * 2);        // 31.9 MB
    bf16* fc1t  = (bf16*)alloc((size_t)1024 * 2304 * 2);
    float* feat = (float*)alloc((size_t)1088 * 2304 * 4);       // 10 MB
    bf16* bpad  = (bf16*)alloc((size_t)20 * 66 * 2304 * 2);
    bf16* xbuf  = (bf16*)alloc((size_t)64 * 20 * 2304 * 2);
    bf16* hbuf  = (bf16*)alloc((size_t)1024 * 1024 * 2);
    float* s1   = (float*)alloc(512 * 4);
    float* t1   = (float*)alloc(512 * 4);
    float* s2   = (float*)alloc(256 * 4);
    float* t2   = (float*)alloc(256 * 4);
    int* rb1    = (int*)alloc(9856 * 4);
    int* rb2    = (int*)alloc(9856 * 4);
    int* rb1d   = (int*)alloc(1280 * 4);
    int* rbfc   = (int*)alloc(1024 * 4);

    // zero padded activation buffers (borders must be 0)
    hipMemsetAsync(apad1, 0, (size_t)1088 * 25 * 1024 * 2, stream);
    hipMemsetAsync(apad2, 0, (size_t)1088 * 25 * 512 * 2, stream);
    hipMemsetAsync(bpad, 0, (size_t)20 * 66 * 2304 * 2, stream);

    // weight prep
    repack_w<<<(512 * 1024 * 9 + 255) / 256, 256, 0, stream>>>(conv1_w, wb1, 512, 1024, 9);
    repack_w<<<(256 * 512 * 9 + 255) / 256, 256, 0, stream>>>(conv2_w, wb2, 256, 512, 9);
    repack_w<<<(2304 * 2304 * 3 + 255) / 256, 256, 0, stream>>>(conv1d_w, wb1d, 2304, 2304, 3);
    transpose_fc1<<<(1024 * 2304 + 255) / 256, 256, 0, stream>>>(fc1_w, fc1t);
    bn_fold<<<2, 256, 0, stream>>>(bn1_g, bn1_b, bn1_m, bn1_v, s1, t1, 512);
    bn_fold<<<1, 256, 0, stream>>>(bn2_g, bn2_b, bn2_m, bn2_v, s2, t2, 256);
    setup_rowbase<<<(9856 + 255) / 256, 256, 0, stream>>>(rb1, rb2, rb1d, rbfc, pidx);

    // channels-last bf16 fmap, then roi_align for all 1088 boxes
    transpose_fmap<<<dim3(7, 32, 64), dim3(32, 8), 0, stream>>>(fmap, fml);
    roi_kernel2<<<1088, 128, 0, stream>>>(fml, boxes, apad1);

    // conv1: M=9792 N=512 K=9216 (616 blocks, no split)
    gemm_k<0, 1><<<dim3(8, 77, 1), 256, 0, stream>>>(apad1, rb1, wb1, apad2, s1, t1);
    // conv2: M=9792 N=256 K=4608, split-K x2 -> 616 blocks
    gemm_k<1, 2><<<dim3(4, 77, 2), 256, 0, stream>>>(apad2, rb2, wb2, part2, nullptr, nullptr);
    reduce_k<0><<<(9792 * 256 + 255) / 256, 256, 0, stream>>>(part2, feat, s2, t2);
    // assemble behavior (padded over t)
    assemble<<<dim3(64, 20), 256, 0, stream>>>(feat, pidx, bpad);
    // conv1d: M=1280 N=2304 K=6912, split-K x6 -> 2160 blocks
    gemm_k<2, 6><<<dim3(36, 10, 6), 256, 0, stream>>>(bpad, rb1d, wb1d, part1d, nullptr, nullptr);
    reduce_k<1><<<(1280 * 2304 + 255) / 256, 256, 0, stream>>>(part1d, xbuf, conv1d_b, nullptr);
    // fc1 (+person gather via rowbase): M=1024 N=1024 K=2304, split-K x4 -> 512 blocks
    gemm_k<3, 4><<<dim3(16, 8, 4), 256, 0, stream>>>(xbuf, rbfc, fc1t, partfc, nullptr, nullptr);
    reduce_k<2><<<(1024 * 1024 + 255) / 256, 256, 0, stream>>>(partfc, hbuf, fc1_b, nullptr);
    // fc2
    fc2_kernel<<<(1024 * 30 + 255) / 256, 256, 0, stream>>>(hbuf, fc2_w, fc2_b, out);
    (void)in_sizes; (void)n_in; (void)out_size; (void)ws_size;
}

// Round 4
// 666.559 us; speedup vs baseline: 1.9211x; 1.1160x over previous
//
#include <hip/hip_runtime.h>
#include <hip/hip_bf16.h>
#include <cstdint>
#include <cstddef>

typedef __bf16 bf16;
typedef __bf16 bf16x8 __attribute__((ext_vector_type(8)));
typedef float f32x4 __attribute__((ext_vector_type(4)));

// ---------------- weight repack (coalesced): w[OC][IC][NT] -> out[OC][NT*IC] bf16
// thread per (oc,ic): reads NT contiguous floats, writes NT coalesced bf16 streams
template <int NT>
__global__ void __launch_bounds__(256) repack_w(const float* __restrict__ w, bf16* __restrict__ out,
                                                int OC, int IC) {
    int idx = blockIdx.x * 256 + threadIdx.x;
    if (idx >= OC * IC) return;
    int oc = idx / IC;
    int ic = idx - oc * IC;
    const float* src = w + (size_t)idx * NT;
    #pragma unroll
    for (int t = 0; t < NT; t++)
        out[(size_t)oc * NT * IC + t * IC + ic] = (bf16)src[t];
}

// ---------------- fc1_w [2304][1024] -> fc1t [1024][2304] bf16 (LDS tiled, both sides coalesced)
__global__ void __launch_bounds__(256) transpose_fc1(const float* __restrict__ w, bf16* __restrict__ out) {
    __shared__ float t[32][33];
    int iT = blockIdx.x * 32;   // 72 tiles over 2304
    int oT = blockIdx.y * 32;   // 32 tiles over 1024
    int tx = threadIdx.x, ty = threadIdx.y;   // 32 x 8
    #pragma unroll
    for (int j = 0; j < 4; j++)
        t[ty + j * 8][tx] = w[(size_t)(iT + ty + j * 8) * 1024 + oT + tx];
    __syncthreads();
    #pragma unroll
    for (int j = 0; j < 4; j++)
        out[(size_t)(oT + ty + j * 8) * 2304 + iT + tx] = (bf16)t[tx][ty + j * 8];
}

// ---------------- fc2_w [1024][30] -> w2t [30][1024] bf16 (tiny)
__global__ void __launch_bounds__(256) transpose_w2(const float* __restrict__ w, bf16* __restrict__ out) {
    int idx = blockIdx.x * 256 + threadIdx.x;
    if (idx >= 30 * 1024) return;
    int n = idx / 1024, k = idx - n * 1024;
    out[idx] = (bf16)w[(size_t)k * 30 + n];
}

// ---------------- BN fold: s = g*rsqrt(v+eps), t = b - m*s
__global__ void __launch_bounds__(256) bn_fold(const float* __restrict__ g, const float* __restrict__ b,
                                               const float* __restrict__ m, const float* __restrict__ v,
                                               float* __restrict__ s, float* __restrict__ t, int n) {
    int i = blockIdx.x * 256 + threadIdx.x;
    if (i >= n) return;
    float sc = g[i] * rsqrtf(v[i] + 1e-5f);
    s[i] = sc;
    t[i] = b[i] - m[i] * sc;
}

// ---------------- rowbase arrays for the 4 GEMMs
__global__ void __launch_bounds__(256) setup_rowbase(int* __restrict__ rb1, int* __restrict__ rb2,
                                                     int* __restrict__ rb1d, int* __restrict__ rbfc,
                                                     const int* __restrict__ pidx) {
    int m = blockIdx.x * 256 + threadIdx.x;
    if (m < 9856) {                       // conv1/conv2: M=9792 padded to 77*128
        int mm = m < 9792 ? m : 0;
        int img = mm / 9, pos = mm - img * 9;
        int base = img * 25 + (pos / 3) * 5 + (pos % 3);   // padded 5x5, tap (0,0) origin
        rb1[m] = base * 1024;
        rb2[m] = base * 512;
    }
    if (m < 1280) {                       // conv1d rows: m = p*64 + t
        int p = m >> 6, t = m & 63;
        rb1d[m] = (p * 66 + t) * 2304;
    }
    if (m < 1024) {                       // fc1 rows: m = b*16 + n_, gather person_idx
        int b = m >> 4;
        rbfc[m] = (b * 20 + pidx[m]) * 2304;
    }
}

// ---------------- fmap [64][1024][196] f32 -> fml [64][196][1024] bf16 (LDS tile transpose)
__global__ void __launch_bounds__(256) transpose_fmap(const float* __restrict__ fmap, bf16* __restrict__ fml) {
    __shared__ float t[32][33];
    int img = blockIdx.z;
    int hwT = blockIdx.x * 32;   // 7 tiles (196)
    int cT  = blockIdx.y * 32;   // 32 tiles (1024)
    int tx = threadIdx.x, ty = threadIdx.y;   // 32 x 8
    #pragma unroll
    for (int j = 0; j < 4; j++) {
        int c = cT + ty + j * 8;
        int hw = hwT + tx;
        if (hw < 196)
            t[ty + j * 8][tx] = fmap[((size_t)img * 1024 + c) * 196 + hw];
    }
    __syncthreads();
    #pragma unroll
    for (int j = 0; j < 4; j++) {
        int hw = hwT + ty + j * 8;
        int c = cT + tx;
        if (hw < 196)
            fml[((size_t)img * 196 + hw) * 1024 + c] = (bf16)t[tx][ty + j * 8];
    }
}

// ---------------- roi_align (channels-last) -> apad1[1088][5][5][1024] bf16 interior
__global__ void __launch_bounds__(128) roi_kernel2(const bf16* __restrict__ fml, const float* __restrict__ boxes,
                                                   bf16* __restrict__ apad) {
    int box = blockIdx.x;
    int tid = threadIdx.x;        // 128 lanes, lane owns 8 channels
    float x1, y1, x2, y2;
    int img;
    if (box < 64) { img = box; x1 = 0.f; y1 = 0.f; x2 = 14.f; y2 = 14.f; }
    else {
        int ib = box - 64;
        img = ib >> 4;
        const float* bb = boxes + (size_t)ib * 4;
        x1 = bb[0]; y1 = bb[1]; x2 = bb[2]; y2 = bb[3];
    }
    float rw = fmaxf(x2 - x1, 1.f), rh = fmaxf(y2 - y1, 1.f);
    __shared__ float swy[6], swx[6];
    __shared__ int sy0[6], sx0[6];
    if (tid < 6) {
        int i = tid;
        float pos = ((float)i + 0.5f) * 0.5f;
        float yv = fminf(fmaxf(y1 + pos * (rh * (1.f / 3.f)), 0.f), 13.f);
        float y0 = floorf(yv);
        sy0[i] = (int)y0; swy[i] = yv - y0;
        float xv = fminf(fmaxf(x1 + pos * (rw * (1.f / 3.f)), 0.f), 13.f);
        float x0 = floorf(xv);
        sx0[i] = (int)x0; swx[i] = xv - x0;
    }
    __syncthreads();
    const bf16* base = fml + (size_t)img * 196 * 1024 + tid * 8;
    #pragma unroll
    for (int oy = 0; oy < 3; oy++) {
        #pragma unroll
        for (int ox = 0; ox < 3; ox++) {
            float acc[8];
            #pragma unroll
            for (int e = 0; e < 8; e++) acc[e] = 0.f;
            #pragma unroll
            for (int dy = 0; dy < 2; dy++) {
                int sy = 2 * oy + dy;
                int y0 = sy0[sy]; float wy = swy[sy];
                int y1i = min(y0 + 1, 13);
                #pragma unroll
                for (int dx = 0; dx < 2; dx++) {
                    int sx = 2 * ox + dx;
                    int x0 = sx0[sx]; float wx = swx[sx];
                    int x1i = min(x0 + 1, 13);
                    bf16x8 f00 = *(const bf16x8*)(base + (size_t)(y0 * 14 + x0) * 1024);
                    bf16x8 f01 = *(const bf16x8*)(base + (size_t)(y0 * 14 + x1i) * 1024);
                    bf16x8 f10 = *(const bf16x8*)(base + (size_t)(y1i * 14 + x0) * 1024);
                    bf16x8 f11 = *(const bf16x8*)(base + (size_t)(y1i * 14 + x1i) * 1024);
                    float w00 = (1.f - wy) * (1.f - wx), w01 = (1.f - wy) * wx;
                    float w10 = wy * (1.f - wx),         w11 = wy * wx;
                    #pragma unroll
                    for (int e = 0; e < 8; e++)
                        acc[e] += w00 * (float)f00[e] + w01 * (float)f01[e]
                                + w10 * (float)f10[e] + w11 * (float)f11[e];
                }
            }
            bf16x8 o;
            #pragma unroll
            for (int e = 0; e < 8; e++) o[e] = (bf16)(acc[e] * 0.25f);
            *(bf16x8*)(apad + ((size_t)box * 25 + (oy + 1) * 5 + (ox + 1)) * 1024 + tid * 8) = o;
        }
    }
}

// ---------------- behavior assembly: bpad[p][t+1][f] = g_feat[t] + sum_{n: idx==p} i_feat[t,n]
__global__ void __launch_bounds__(256) assemble(const float* __restrict__ feat, const int* __restrict__ pidx,
                                                bf16* __restrict__ bpad) {
    int b = blockIdx.x;   // 0..63 (time index)
    int p = blockIdx.y;   // 0..19
    __shared__ int idxs[16];
    if (threadIdx.x < 16) idxs[threadIdx.x] = pidx[b * 16 + threadIdx.x];
    __syncthreads();
    const float* g = feat + (size_t)b * 2304;
    for (int f = threadIdx.x; f < 2304; f += 256) {
        float v = g[f];
        #pragma unroll
        for (int n = 0; n < 16; n++)
            if (idxs[n] == p) v += feat[(size_t)(64 + b * 16 + n) * 2304 + f];
        bpad[((size_t)p * 66 + (b + 1)) * 2304 + f] = (bf16)v;
    }
}

// ---------------- unified implicit-GEMM MFMA kernel (XOR-swizzled LDS, split-K)
// C[M][N] = sum_k A[rowbase[m] + posOff(k/Cin)*Cin + k%Cin] * B[n*K + k]
// BM=128, BN=64, BK=64; 4 waves, each wave: 32 rows x 64 cols (2x4 16x16x32 tiles)
// LDS: row stride 64 elems, chunk c of row r at column (c ^ (r&7))*8 -> conflict floor.
template <int MODE, int NSPLIT>
__global__ void __launch_bounds__(256) gemm_k(const bf16* __restrict__ A, const int* __restrict__ rowbase,
                                              const bf16* __restrict__ Bw, void* __restrict__ outp,
                                              const float* __restrict__ c0, const float* __restrict__ c1) {
    constexpr int K   = MODE == 0 ? 9216 : MODE == 1 ? 4608 : MODE == 2 ? 6912 : 2304;
    constexpr int N   = MODE == 0 ? 512  : MODE == 1 ? 256  : MODE == 2 ? 2304 : 1024;
    constexpr int Cin = MODE == 0 ? 1024 : MODE == 1 ? 512  : 2304;
    constexpr int M   = MODE <= 1 ? 9792 : MODE == 2 ? 1280 : 1024;
    constexpr bool C3 = (MODE <= 1);
    constexpr bool MPAD = (M % 128) != 0;
    constexpr int KTS = (K / 64) / NSPLIT;     // kt iterations per slice

    const int bm = blockIdx.y * 128;
    const int bn = blockIdx.x * 64;
    const int z  = blockIdx.z;
    const int tid = threadIdx.x;
    const int lane = tid & 63, wave = tid >> 6;
    const int q = lane >> 4, ln16 = lane & 15;

    __shared__ __align__(16) bf16 As[128 * 64];
    __shared__ __align__(16) bf16 Bs[64 * 64];
    __shared__ int rb[128];

    if (tid < 128) rb[tid] = rowbase[bm + tid];

    f32x4 acc[2][4];
    #pragma unroll
    for (int mt = 0; mt < 2; mt++)
        #pragma unroll
        for (int nt = 0; nt < 4; nt++)
            acc[mt][nt] = (f32x4){0.f, 0.f, 0.f, 0.f};

    for (int kt = z * KTS; kt < z * KTS + KTS; kt++) {
        const int k0 = kt * 64;
        const int tap = k0 / Cin;                 // constexpr divisor -> cheap
        const int inner = k0 - tap * Cin;
        const int poff = C3 ? ((tap / 3) * 5 + (tap % 3)) : tap;
        const int aoff = poff * Cin + inner;

        __syncthreads();   // protect LDS (and rb on iter 0) before overwrite
        #pragma unroll
        for (int u = 0; u < 4; u++) {            // stage A: 128 rows x 8 chunks
            int id = tid + u * 256;
            int row = id >> 3, c = id & 7;
            const bf16* src = A + (size_t)(rb[row] + aoff + c * 8);
            *(bf16x8*)(As + row * 64 + ((c ^ (row & 7)) << 3)) = *(const bf16x8*)src;
        }
        #pragma unroll
        for (int u = 0; u < 2; u++) {            // stage B: 64 rows x 8 chunks
            int id = tid + u * 256;
            int row = id >> 3, c = id & 7;
            const bf16* src = Bw + (size_t)(bn + row) * K + k0 + c * 8;
            *(bf16x8*)(Bs + row * 64 + ((c ^ (row & 7)) << 3)) = *(const bf16x8*)src;
        }
        __syncthreads();

        #pragma unroll
        for (int s = 0; s < 2; s++) {
            bf16x8 af[2], bfr[4];
            #pragma unroll
            for (int mt = 0; mt < 2; mt++) {
                int r = wave * 32 + mt * 16 + ln16;
                af[mt] = *(const bf16x8*)(As + r * 64 + (((4 * s + q) ^ (r & 7)) << 3));
            }
            #pragma unroll
            for (int nt = 0; nt < 4; nt++) {
                int r = nt * 16 + ln16;
                bfr[nt] = *(const bf16x8*)(Bs + r * 64 + (((4 * s + q) ^ (r & 7)) << 3));
            }
            #pragma unroll
            for (int mt = 0; mt < 2; mt++)
                #pragma unroll
                for (int nt = 0; nt < 4; nt++)
                    acc[mt][nt] = __builtin_amdgcn_mfma_f32_16x16x32_bf16(af[mt], bfr[nt], acc[mt][nt], 0, 0, 0);
        }
    }

    // epilogue: C/D layout col=lane&15, row=quad*4+reg; all modes write fp32 partials
    #pragma unroll
    for (int mt = 0; mt < 2; mt++) {
        int gmBase = bm + wave * 32 + mt * 16 + q * 4;
        #pragma unroll
        for (int r = 0; r < 4; r++) {
            int gm = gmBase + r;
            if (MPAD && gm >= M) continue;
            #pragma unroll
            for (int nt = 0; nt < 4; nt++) {
                int gn = bn + nt * 16 + ln16;
                ((float*)outp)[((size_t)z * M + gm) * N + gn] = acc[mt][nt][r];
            }
        }
    }
    (void)c0; (void)c1;
}

// ---------------- split-K reducers
// RMODE 0: conv2 partials -> feat fp32 (BN+leaky, scatter [img][oc*9+pos]), S=3
// RMODE 1: conv1d partials -> xbuf bf16 (+bias, [t][p][oc]), S=4
// RMODE 2: fc1 partials -> hbuf bf16 (+bias, relu), S=4
// RMODE 3: conv1 partials -> apad2 bf16 interior (BN+leaky), S=3
template <int RMODE>
__global__ void __launch_bounds__(256) reduce_k(const float* __restrict__ part, void* __restrict__ outp,
                                                const float* __restrict__ c0, const float* __restrict__ c1) {
    constexpr int M = RMODE == 0 ? 9792 : RMODE == 1 ? 1280 : RMODE == 2 ? 1024 : 9792;
    constexpr int N = RMODE == 0 ? 256  : RMODE == 1 ? 2304 : RMODE == 2 ? 1024 : 512;
    constexpr int S = RMODE == 0 ? 3    : RMODE == 1 ? 4    : RMODE == 2 ? 4    : 3;
    int idx = blockIdx.x * 256 + threadIdx.x;
    if (idx >= M * N) return;
    int m = idx / N, n = idx - m * N;
    float v = 0.f;
    #pragma unroll
    for (int s = 0; s < S; s++) v += part[(size_t)s * M * N + idx];
    if constexpr (RMODE == 0) {
        v = v * c0[n] + c1[n];
        v = v > 0.f ? v : 0.1f * v;
        int img = m / 9, pos = m - img * 9;
        ((float*)outp)[(size_t)img * 2304 + n * 9 + pos] = v;
    } else if constexpr (RMODE == 1) {
        v += c0[n];
        int p = m >> 6, t = m & 63;
        ((bf16*)outp)[((size_t)t * 20 + p) * 2304 + n] = (bf16)v;
    } else if constexpr (RMODE == 2) {
        v = fmaxf(v + c0[n], 0.f);
        ((bf16*)outp)[idx] = (bf16)v;
    } else {
        v = v * c0[n] + c1[n];
        v = v > 0.f ? v : 0.1f * v;
        int img = m / 9, pos = m - img * 9;
        ((bf16*)outp)[(size_t)(img * 25 + (pos / 3 + 1) * 5 + (pos % 3 + 1)) * 512 + n] = (bf16)v;
    }
}

// ---------------- fc2: out[1024][30] = h[1024][1024] @ w2t[30][1024]^T + b2
// block = 8 m-rows x 32 lanes (n); h row broadcast, w2t rows L2-hot (61 KB)
__global__ void __launch_bounds__(256) fc2_kernel(const bf16* __restrict__ h, const bf16* __restrict__ w2t,
                                                  const float* __restrict__ b2, float* __restrict__ out) {
    int tid = threadIdx.x;
    int m = blockIdx.x * 8 + (tid >> 5);
    int n = tid & 31;
    int n2 = n < 30 ? n : 29;
    const bf16* hr = h + (size_t)m * 1024;
    const bf16* wr = w2t + (size_t)n2 * 1024;
    float acc = 0.f;
    for (int k = 0; k < 1024; k += 8) {
        bf16x8 hv = *(const bf16x8*)(hr + k);
        bf16x8 wv = *(const bf16x8*)(wr + k);
        #pragma unroll
        for (int e = 0; e < 8; e++) acc += (float)hv[e] * (float)wv[e];
    }
    if (n < 30) out[(size_t)m * 30 + n] = acc + b2[n];
}

extern "C" void kernel_launch(void* const* d_in, const int* in_sizes, int n_in,
                              void* d_out, int out_size, void* d_ws, size_t ws_size,
                              hipStream_t stream) {
    const float* fmap     = (const float*)d_in[0];
    const float* boxes    = (const float*)d_in[1];
    const int*   pidx     = (const int*)d_in[2];
    const float* conv1_w  = (const float*)d_in[3];
    const float* bn1_g    = (const float*)d_in[4];
    const float* bn1_b    = (const float*)d_in[5];
    const float* bn1_m    = (const float*)d_in[6];
    const float* bn1_v    = (const float*)d_in[7];
    const float* conv2_w  = (const float*)d_in[8];
    const float* bn2_g    = (const float*)d_in[9];
    const float* bn2_b    = (const float*)d_in[10];
    const float* bn2_m    = (const float*)d_in[11];
    const float* bn2_v    = (const float*)d_in[12];
    const float* conv1d_w = (const float*)d_in[13];
    const float* conv1d_b = (const float*)d_in[14];
    const float* fc1_w    = (const float*)d_in[15];
    const float* fc1_b    = (const float*)d_in[16];
    const float* fc2_w    = (const float*)d_in[17];
    const float* fc2_b    = (const float*)d_in[18];
    float* out = (float*)d_out;

    char* ws = (char*)d_ws;

    // ---- exact-lifetime arena (peak 171.7 MB; proven budget >= 181.8 MB) ----
    // smalls @ [0, 98304)
    float* s1   = (float*)(ws + 0);
    float* t1   = (float*)(ws + 2048);
    float* s2   = (float*)(ws + 4096);
    float* t2   = (float*)(ws + 5120);
    int*   rb1  = (int*)(ws + 6144);
    int*   rb2  = (int*)(ws + 45568);
    int*   rb1d = (int*)(ws + 84992);
    int*   rbfc = (int*)(ws + 90112);
    // R_A @ [98304, 60260352): rotating — fml(->roi), part1(conv1->red1),
    //   part2(conv2->red2), part1d(conv1d->red1d), partfc(fc1->redfc)
    bf16*  fml    = (bf16*)(ws + 98304);
    float* part1  = (float*)(ws + 98304);   // 3 x 9792 x 512 = 60.16 MB
    float* part2  = (float*)(ws + 98304);   // 3 x 9792 x 256 = 30.08 MB
    float* part1d = (float*)(ws + 98304);   // 4 x 1280 x 2304 = 47.19 MB
    float* partfc = (float*)(ws + 98304);   // 4 x 1024 x 1024 = 16.78 MB
    // R_B @ [60260352, 115965952): apad1 (roi->conv1); reused after conv1:
    bf16*  apad1  = (bf16*)(ws + 60260352);     // 55.71 MB
    bf16*  wb1d   = (bf16*)(ws + 60260352);     // 31.85 MB (repack after conv1)
    bf16*  fc1t   = (bf16*)(ws + 92110848);     // 4.72 MB
    bf16*  xbuf   = (bf16*)(ws + 96829440);     // 5.90 MB
    bf16*  hbuf   = (bf16*)(ws + 102727680);    // 2.10 MB
    bf16*  w2t    = (bf16*)(ws + 104824832);    // 61 KB
    // dedicated regions
    bf16*  wb1    = (bf16*)(ws + 115965952);    // 9.44 MB
    bf16*  wb2    = (bf16*)(ws + 125403136);    // 2.36 MB
    bf16*  apad2  = (bf16*)(ws + 127762432);    // 27.85 MB
    float* feat   = (float*)(ws + 155615232);   // 10.03 MB
    bf16*  bpad   = (bf16*)(ws + 165642240);    // 6.08 MB  (end 171724800)

    // zero padded activation buffers (borders must stay 0)
    hipMemsetAsync(apad1, 0, (size_t)1088 * 25 * 1024 * 2, stream);
    hipMemsetAsync(apad2, 0, (size_t)1088 * 25 * 512 * 2, stream);
    hipMemsetAsync(bpad, 0, (size_t)20 * 66 * 2304 * 2, stream);

    // prep needed before conv1
    repack_w<9><<<(512 * 1024 + 255) / 256, 256, 0, stream>>>(conv1_w, wb1, 512, 1024);
    repack_w<9><<<(256 * 512 + 255) / 256, 256, 0, stream>>>(conv2_w, wb2, 256, 512);
    bn_fold<<<2, 256, 0, stream>>>(bn1_g, bn1_b, bn1_m, bn1_v, s1, t1, 512);
    bn_fold<<<1, 256, 0, stream>>>(bn2_g, bn2_b, bn2_m, bn2_v, s2, t2, 256);
    setup_rowbase<<<(9856 + 255) / 256, 256, 0, stream>>>(rb1, rb2, rb1d, rbfc, pidx);

    // channels-last bf16 fmap, then roi_align for all 1088 boxes
    transpose_fmap<<<dim3(7, 32, 64), dim3(32, 8), 0, stream>>>(fmap, fml);
    roi_kernel2<<<1088, 128, 0, stream>>>(fml, boxes, apad1);

    // conv1: M=9792 N=512 K=9216, split-K x3 -> 1848 blocks
    gemm_k<0, 3><<<dim3(8, 77, 3), 256, 0, stream>>>(apad1, rb1, wb1, part1, nullptr, nullptr);
    reduce_k<3><<<(9792 * 512 + 255) / 256, 256, 0, stream>>>(part1, apad2, s1, t1);

    // prep that overlays dead apad1 (must run after conv1)
    repack_w<3><<<(2304 * 2304 + 255) / 256, 256, 0, stream>>>(conv1d_w, wb1d, 2304, 2304);
    transpose_fc1<<<dim3(72, 32), dim3(32, 8), 0, stream>>>(fc1_w, fc1t);
    transpose_w2<<<(30 * 1024 + 255) / 256, 256, 0, stream>>>(fc2_w, w2t);

    // conv2: M=9792 N=256 K=4608, split-K x3 -> 924 blocks
    gemm_k<1, 3><<<dim3(4, 77, 3), 256, 0, stream>>>(apad2, rb2, wb2, part2, nullptr, nullptr);
    reduce_k<0><<<(9792 * 256 + 255) / 256, 256, 0, stream>>>(part2, feat, s2, t2);
    // assemble behavior (padded over t)
    assemble<<<dim3(64, 20), 256, 0, stream>>>(feat, pidx, bpad);
    // conv1d: M=1280 N=2304 K=6912, split-K x4 -> 1440 blocks
    gemm_k<2, 4><<<dim3(36, 10, 4), 256, 0, stream>>>(bpad, rb1d, wb1d, part1d, nullptr, nullptr);
    reduce_k<1><<<(1280 * 2304 + 255) / 256, 256, 0, stream>>>(part1d, xbuf, conv1d_b, nullptr);
    // fc1 (+person gather via rowbase): M=1024 N=1024 K=2304, split-K x4 -> 512 blocks
    gemm_k<3, 4><<<dim3(16, 8, 4), 256, 0, stream>>>(xbuf, rbfc, fc1t, partfc, nullptr, nullptr);
    reduce_k<2><<<(1024 * 1024 + 255) / 256, 256, 0, stream>>>(partfc, hbuf, fc1_b, nullptr);
    // fc2
    fc2_kernel<<<128, 256, 0, stream>>>(hbuf, w2t, fc2_b, out);
    (void)in_sizes; (void)n_in; (void)out_size; (void)ws_size;
}

// Round 5
// 623.672 us; speedup vs baseline: 2.0532x; 1.0688x over previous
//
#include <hip/hip_runtime.h>
#include <hip/hip_bf16.h>
#include <cstdint>
#include <cstddef>

typedef __bf16 bf16;
typedef __bf16 bf16x8 __attribute__((ext_vector_type(8)));
typedef float f32x4 __attribute__((ext_vector_type(4)));

// async global->LDS DMA, 16B per lane; lds dest wave-uniform base + lane*16
__device__ __forceinline__ void gload_lds16(const bf16* g, bf16* l) {
    __builtin_amdgcn_global_load_lds((const __attribute__((address_space(1))) void*)g,
                                     (__attribute__((address_space(3))) void*)l, 16, 0, 0);
}

// ---------------- weight repack (coalesced): w[OC][IC][NT] -> out[OC][NT*IC] bf16
template <int NT>
__global__ void __launch_bounds__(256) repack_w(const float* __restrict__ w, bf16* __restrict__ out,
                                                int OC, int IC) {
    int idx = blockIdx.x * 256 + threadIdx.x;
    if (idx >= OC * IC) return;
    int oc = idx / IC;
    int ic = idx - oc * IC;
    const float* src = w + (size_t)idx * NT;
    #pragma unroll
    for (int t = 0; t < NT; t++)
        out[(size_t)oc * NT * IC + t * IC + ic] = (bf16)src[t];
}

// ---------------- fc1_w [2304][1024] -> fc1t [1024][2304] bf16 (LDS tiled)
__global__ void __launch_bounds__(256) transpose_fc1(const float* __restrict__ w, bf16* __restrict__ out) {
    __shared__ float t[32][33];
    int iT = blockIdx.x * 32;
    int oT = blockIdx.y * 32;
    int tx = threadIdx.x, ty = threadIdx.y;   // 32 x 8
    #pragma unroll
    for (int j = 0; j < 4; j++)
        t[ty + j * 8][tx] = w[(size_t)(iT + ty + j * 8) * 1024 + oT + tx];
    __syncthreads();
    #pragma unroll
    for (int j = 0; j < 4; j++)
        out[(size_t)(oT + ty + j * 8) * 2304 + iT + tx] = (bf16)t[tx][ty + j * 8];
}

// ---------------- fc2_w [1024][30] -> w2t [30][1024] bf16 (tiny)
__global__ void __launch_bounds__(256) transpose_w2(const float* __restrict__ w, bf16* __restrict__ out) {
    int idx = blockIdx.x * 256 + threadIdx.x;
    if (idx >= 30 * 1024) return;
    int n = idx / 1024, k = idx - n * 1024;
    out[idx] = (bf16)w[(size_t)k * 30 + n];
}

// ---------------- BN fold
__global__ void __launch_bounds__(256) bn_fold(const float* __restrict__ g, const float* __restrict__ b,
                                               const float* __restrict__ m, const float* __restrict__ v,
                                               float* __restrict__ s, float* __restrict__ t, int n) {
    int i = blockIdx.x * 256 + threadIdx.x;
    if (i >= n) return;
    float sc = g[i] * rsqrtf(v[i] + 1e-5f);
    s[i] = sc;
    t[i] = b[i] - m[i] * sc;
}

// ---------------- rowbase arrays
__global__ void __launch_bounds__(256) setup_rowbase(int* __restrict__ rb1, int* __restrict__ rb2,
                                                     int* __restrict__ rb1d, int* __restrict__ rbfc,
                                                     const int* __restrict__ pidx) {
    int m = blockIdx.x * 256 + threadIdx.x;
    if (m < 9856) {
        int mm = m < 9792 ? m : 0;
        int img = mm / 9, pos = mm - img * 9;
        int base = img * 25 + (pos / 3) * 5 + (pos % 3);
        rb1[m] = base * 1024;
        rb2[m] = base * 512;
    }
    if (m < 1280) {
        int p = m >> 6, t = m & 63;
        rb1d[m] = (p * 66 + t) * 2304;
    }
    if (m < 1024) {
        int b = m >> 4;
        rbfc[m] = (b * 20 + pidx[m]) * 2304;
    }
}

// ---------------- fmap transpose to channels-last bf16
__global__ void __launch_bounds__(256) transpose_fmap(const float* __restrict__ fmap, bf16* __restrict__ fml) {
    __shared__ float t[32][33];
    int img = blockIdx.z;
    int hwT = blockIdx.x * 32;
    int cT  = blockIdx.y * 32;
    int tx = threadIdx.x, ty = threadIdx.y;
    #pragma unroll
    for (int j = 0; j < 4; j++) {
        int c = cT + ty + j * 8;
        int hw = hwT + tx;
        if (hw < 196)
            t[ty + j * 8][tx] = fmap[((size_t)img * 1024 + c) * 196 + hw];
    }
    __syncthreads();
    #pragma unroll
    for (int j = 0; j < 4; j++) {
        int hw = hwT + ty + j * 8;
        int c = cT + tx;
        if (hw < 196)
            fml[((size_t)img * 196 + hw) * 1024 + c] = (bf16)t[tx][ty + j * 8];
    }
}

// ---------------- roi_align (channels-last) -> apad1 interior
__global__ void __launch_bounds__(128) roi_kernel2(const bf16* __restrict__ fml, const float* __restrict__ boxes,
                                                   bf16* __restrict__ apad) {
    int box = blockIdx.x;
    int tid = threadIdx.x;
    float x1, y1, x2, y2;
    int img;
    if (box < 64) { img = box; x1 = 0.f; y1 = 0.f; x2 = 14.f; y2 = 14.f; }
    else {
        int ib = box - 64;
        img = ib >> 4;
        const float* bb = boxes + (size_t)ib * 4;
        x1 = bb[0]; y1 = bb[1]; x2 = bb[2]; y2 = bb[3];
    }
    float rw = fmaxf(x2 - x1, 1.f), rh = fmaxf(y2 - y1, 1.f);
    __shared__ float swy[6], swx[6];
    __shared__ int sy0[6], sx0[6];
    if (tid < 6) {
        int i = tid;
        float pos = ((float)i + 0.5f) * 0.5f;
        float yv = fminf(fmaxf(y1 + pos * (rh * (1.f / 3.f)), 0.f), 13.f);
        float y0 = floorf(yv);
        sy0[i] = (int)y0; swy[i] = yv - y0;
        float xv = fminf(fmaxf(x1 + pos * (rw * (1.f / 3.f)), 0.f), 13.f);
        float x0 = floorf(xv);
        sx0[i] = (int)x0; swx[i] = xv - x0;
    }
    __syncthreads();
    const bf16* base = fml + (size_t)img * 196 * 1024 + tid * 8;
    #pragma unroll
    for (int oy = 0; oy < 3; oy++) {
        #pragma unroll
        for (int ox = 0; ox < 3; ox++) {
            float acc[8];
            #pragma unroll
            for (int e = 0; e < 8; e++) acc[e] = 0.f;
            #pragma unroll
            for (int dy = 0; dy < 2; dy++) {
                int sy = 2 * oy + dy;
                int y0 = sy0[sy]; float wy = swy[sy];
                int y1i = min(y0 + 1, 13);
                #pragma unroll
                for (int dx = 0; dx < 2; dx++) {
                    int sx = 2 * ox + dx;
                    int x0 = sx0[sx]; float wx = swx[sx];
                    int x1i = min(x0 + 1, 13);
                    bf16x8 f00 = *(const bf16x8*)(base + (size_t)(y0 * 14 + x0) * 1024);
                    bf16x8 f01 = *(const bf16x8*)(base + (size_t)(y0 * 14 + x1i) * 1024);
                    bf16x8 f10 = *(const bf16x8*)(base + (size_t)(y1i * 14 + x0) * 1024);
                    bf16x8 f11 = *(const bf16x8*)(base + (size_t)(y1i * 14 + x1i) * 1024);
                    float w00 = (1.f - wy) * (1.f - wx), w01 = (1.f - wy) * wx;
                    float w10 = wy * (1.f - wx),         w11 = wy * wx;
                    #pragma unroll
                    for (int e = 0; e < 8; e++)
                        acc[e] += w00 * (float)f00[e] + w01 * (float)f01[e]
                                + w10 * (float)f10[e] + w11 * (float)f11[e];
                }
            }
            bf16x8 o;
            #pragma unroll
            for (int e = 0; e < 8; e++) o[e] = (bf16)(acc[e] * 0.25f);
            *(bf16x8*)(apad + ((size_t)box * 25 + (oy + 1) * 5 + (ox + 1)) * 1024 + tid * 8) = o;
        }
    }
}

// ---------------- behavior assembly
__global__ void __launch_bounds__(256) assemble(const float* __restrict__ feat, const int* __restrict__ pidx,
                                                bf16* __restrict__ bpad) {
    int b = blockIdx.x;
    int p = blockIdx.y;
    __shared__ int idxs[16];
    if (threadIdx.x < 16) idxs[threadIdx.x] = pidx[b * 16 + threadIdx.x];
    __syncthreads();
    const float* g = feat + (size_t)b * 2304;
    for (int f = threadIdx.x; f < 2304; f += 256) {
        float v = g[f];
        #pragma unroll
        for (int n = 0; n < 16; n++)
            if (idxs[n] == p) v += feat[(size_t)(64 + b * 16 + n) * 2304 + f];
        bpad[((size_t)p * 66 + (b + 1)) * 2304 + f] = (bf16)v;
    }
}

// ---------------- implicit-GEMM MFMA, m97 structure: 128x128 tile, global_load_lds staging
// 4 waves in 2x2; wave = 64x64 (4x4 16x16x32 tiles, acc[4][4]); BK=64.
// LDS row-major [row][64] (NO pad/swizzle: global_load_lds dest = base + lane*16).
// All modes write fp32 partials part[z][M][N]; reducers fuse epilogues.
template <int MODE, int NSPLIT>
__global__ void __launch_bounds__(256) gemm_k(const bf16* __restrict__ A, const int* __restrict__ rowbase,
                                              const bf16* __restrict__ Bw, float* __restrict__ outp) {
    constexpr int K   = MODE == 0 ? 9216 : MODE == 1 ? 4608 : MODE == 2 ? 6912 : 2304;
    constexpr int N   = MODE == 0 ? 512  : MODE == 1 ? 256  : MODE == 2 ? 2304 : 1024;
    constexpr int Cin = MODE == 0 ? 1024 : MODE == 1 ? 512  : 2304;
    constexpr int M   = MODE <= 1 ? 9792 : MODE == 2 ? 1280 : 1024;
    constexpr bool C3 = (MODE <= 1);
    constexpr bool MPAD = (M % 128) != 0;
    constexpr int KTS = (K / 64) / NSPLIT;

    const int bm = blockIdx.y * 128;
    const int bn = blockIdx.x * 128;
    const int z  = blockIdx.z;
    const int tid = threadIdx.x;
    const int lane = tid & 63, wave = tid >> 6;
    const int q = lane >> 4, ln16 = lane & 15;
    const int wr = wave >> 1, wc = wave & 1;

    __shared__ __align__(16) bf16 As[128 * 64];
    __shared__ __align__(16) bf16 Bs[128 * 64];

    // staging setup: wave w stages As rows [w*32,w*32+32) and Bs rows likewise,
    // 4 instrs each of 8 rows (64 lanes x 16B). lane: row += lane>>3, col = (lane&7)*8.
    const int sr = lane >> 3;
    const int scol = (lane & 7) * 8;
    int rbA[4];
    const bf16* gB[4];
    #pragma unroll
    for (int u = 0; u < 4; u++) {
        int row = wave * 32 + u * 8 + sr;
        rbA[u] = rowbase[bm + row];
        gB[u] = Bw + (size_t)(bn + row) * K + scol;
    }

    f32x4 acc[4][4];
    #pragma unroll
    for (int mt = 0; mt < 4; mt++)
        #pragma unroll
        for (int nt = 0; nt < 4; nt++)
            acc[mt][nt] = (f32x4){0.f, 0.f, 0.f, 0.f};

    for (int kt = z * KTS; kt < z * KTS + KTS; kt++) {
        const int k0 = kt * 64;
        const int tap = k0 / Cin;
        const int inner = k0 - tap * Cin;
        const int poff = C3 ? ((tap / 3) * 5 + (tap % 3)) : tap;
        const int aoff = poff * Cin + inner + scol;

        __syncthreads();   // all waves done reading previous tile
        #pragma unroll
        for (int u = 0; u < 4; u++)
            gload_lds16(A + (size_t)(rbA[u] + aoff), As + (wave * 32 + u * 8) * 64);
        #pragma unroll
        for (int u = 0; u < 4; u++)
            gload_lds16(gB[u] + k0, Bs + (wave * 32 + u * 8) * 64);
        __syncthreads();   // drains vmcnt -> staged data visible

        #pragma unroll
        for (int s = 0; s < 2; s++) {
            bf16x8 af[4], bfr[4];
            #pragma unroll
            for (int mt = 0; mt < 4; mt++)
                af[mt] = *(const bf16x8*)(As + (wr * 64 + mt * 16 + ln16) * 64 + s * 32 + q * 8);
            #pragma unroll
            for (int nt = 0; nt < 4; nt++)
                bfr[nt] = *(const bf16x8*)(Bs + (wc * 64 + nt * 16 + ln16) * 64 + s * 32 + q * 8);
            #pragma unroll
            for (int mt = 0; mt < 4; mt++)
                #pragma unroll
                for (int nt = 0; nt < 4; nt++)
                    acc[mt][nt] = __builtin_amdgcn_mfma_f32_16x16x32_bf16(af[mt], bfr[nt], acc[mt][nt], 0, 0, 0);
        }
    }

    // epilogue: C/D layout col=lane&15, row=quad*4+reg; fp32 partials
    #pragma unroll
    for (int mt = 0; mt < 4; mt++) {
        int gmBase = bm + wr * 64 + mt * 16 + q * 4;
        #pragma unroll
        for (int r = 0; r < 4; r++) {
            int gm = gmBase + r;
            if (MPAD && gm >= M) continue;
            #pragma unroll
            for (int nt = 0; nt < 4; nt++) {
                int gn = bn + wc * 64 + nt * 16 + ln16;
                outp[((size_t)z * M + gm) * N + gn] = acc[mt][nt][r];
            }
        }
    }
}

// ---------------- split-K reducers
// RMODE 0: conv2 -> feat fp32 (BN+leaky, scatter [img][oc*9+pos]), S=6
// RMODE 1: conv1d -> xbuf bf16 (+bias, [t][p][oc]), S=4
// RMODE 2: fc1 -> hbuf bf16 (+bias, relu), S=6
// RMODE 3: conv1 -> apad2 bf16 interior (BN+leaky), S=3
template <int RMODE>
__global__ void __launch_bounds__(256) reduce_k(const float* __restrict__ part, void* __restrict__ outp,
                                                const float* __restrict__ c0, const float* __restrict__ c1) {
    constexpr int M = RMODE == 0 ? 9792 : RMODE == 1 ? 1280 : RMODE == 2 ? 1024 : 9792;
    constexpr int N = RMODE == 0 ? 256  : RMODE == 1 ? 2304 : RMODE == 2 ? 1024 : 512;
    constexpr int S = RMODE == 0 ? 6    : RMODE == 1 ? 4    : RMODE == 2 ? 6    : 3;
    int idx = blockIdx.x * 256 + threadIdx.x;
    if (idx >= M * N) return;
    int m = idx / N, n = idx - m * N;
    float v = 0.f;
    #pragma unroll
    for (int s = 0; s < S; s++) v += part[(size_t)s * M * N + idx];
    if constexpr (RMODE == 0) {
        v = v * c0[n] + c1[n];
        v = v > 0.f ? v : 0.1f * v;
        int img = m / 9, pos = m - img * 9;
        ((float*)outp)[(size_t)img * 2304 + n * 9 + pos] = v;
    } else if constexpr (RMODE == 1) {
        v += c0[n];
        int p = m >> 6, t = m & 63;
        ((bf16*)outp)[((size_t)t * 20 + p) * 2304 + n] = (bf16)v;
    } else if constexpr (RMODE == 2) {
        v = fmaxf(v + c0[n], 0.f);
        ((bf16*)outp)[idx] = (bf16)v;
    } else {
        v = v * c0[n] + c1[n];
        v = v > 0.f ? v : 0.1f * v;
        int img = m / 9, pos = m - img * 9;
        ((bf16*)outp)[(size_t)(img * 25 + (pos / 3 + 1) * 5 + (pos % 3 + 1)) * 512 + n] = (bf16)v;
    }
}

// ---------------- fc2
__global__ void __launch_bounds__(256) fc2_kernel(const bf16* __restrict__ h, const bf16* __restrict__ w2t,
                                                  const float* __restrict__ b2, float* __restrict__ out) {
    int tid = threadIdx.x;
    int m = blockIdx.x * 8 + (tid >> 5);
    int n = tid & 31;
    int n2 = n < 30 ? n : 29;
    const bf16* hr = h + (size_t)m * 1024;
    const bf16* wr = w2t + (size_t)n2 * 1024;
    float acc = 0.f;
    for (int k = 0; k < 1024; k += 8) {
        bf16x8 hv = *(const bf16x8*)(hr + k);
        bf16x8 wv = *(const bf16x8*)(wr + k);
        #pragma unroll
        for (int e = 0; e < 8; e++) acc += (float)hv[e] * (float)wv[e];
    }
    if (n < 30) out[(size_t)m * 30 + n] = acc + b2[n];
}

extern "C" void kernel_launch(void* const* d_in, const int* in_sizes, int n_in,
                              void* d_out, int out_size, void* d_ws, size_t ws_size,
                              hipStream_t stream) {
    const float* fmap     = (const float*)d_in[0];
    const float* boxes    = (const float*)d_in[1];
    const int*   pidx     = (const int*)d_in[2];
    const float* conv1_w  = (const float*)d_in[3];
    const float* bn1_g    = (const float*)d_in[4];
    const float* bn1_b    = (const float*)d_in[5];
    const float* bn1_m    = (const float*)d_in[6];
    const float* bn1_v    = (const float*)d_in[7];
    const float* conv2_w  = (const float*)d_in[8];
    const float* bn2_g    = (const float*)d_in[9];
    const float* bn2_b    = (const float*)d_in[10];
    const float* bn2_m    = (const float*)d_in[11];
    const float* bn2_v    = (const float*)d_in[12];
    const float* conv1d_w = (const float*)d_in[13];
    const float* conv1d_b = (const float*)d_in[14];
    const float* fc1_w    = (const float*)d_in[15];
    const float* fc1_b    = (const float*)d_in[16];
    const float* fc2_w    = (const float*)d_in[17];
    const float* fc2_b    = (const float*)d_in[18];
    float* out = (float*)d_out;

    char* ws = (char*)d_ws;

    // ---- exact-lifetime arena (peak 171.7 MB) ----
    float* s1   = (float*)(ws + 0);
    float* t1   = (float*)(ws + 2048);
    float* s2   = (float*)(ws + 4096);
    float* t2   = (float*)(ws + 5120);
    int*   rb1  = (int*)(ws + 6144);
    int*   rb2  = (int*)(ws + 45568);
    int*   rb1d = (int*)(ws + 84992);
    int*   rbfc = (int*)(ws + 90112);
    // R_A rotating @ [98304, 60260352): fml -> part1(S3 x 512) -> part2(S6 x 256)
    //   -> part1d(S4) -> partfc(S6)
    bf16*  fml    = (bf16*)(ws + 98304);
    float* part1  = (float*)(ws + 98304);   // 3 x 9792 x 512 x 4 = 60162048 (exact fit)
    float* part2  = (float*)(ws + 98304);   // 6 x 9792 x 256 x 4 = 60162048 (exact fit)
    float* part1d = (float*)(ws + 98304);   // 4 x 1280 x 2304 x 4 = 47.2 MB
    float* partfc = (float*)(ws + 98304);   // 6 x 1024 x 1024 x 4 = 25.2 MB
    // R_B @ [60260352, ...): apad1 (roi->conv1), then overlaid after conv1:
    bf16*  apad1  = (bf16*)(ws + 60260352);     // 55.71 MB
    bf16*  wb1d   = (bf16*)(ws + 60260352);     // 31.85 MB
    bf16*  fc1t   = (bf16*)(ws + 92110848);
    bf16*  xbuf   = (bf16*)(ws + 96829440);
    bf16*  hbuf   = (bf16*)(ws + 102727680);
    bf16*  w2t    = (bf16*)(ws + 104824832);
    // dedicated
    bf16*  wb1    = (bf16*)(ws + 115965952);
    bf16*  wb2    = (bf16*)(ws + 125403136);
    bf16*  apad2  = (bf16*)(ws + 127762432);
    float* feat   = (float*)(ws + 155615232);
    bf16*  bpad   = (bf16*)(ws + 165642240);

    hipMemsetAsync(apad1, 0, (size_t)1088 * 25 * 1024 * 2, stream);
    hipMemsetAsync(apad2, 0, (size_t)1088 * 25 * 512 * 2, stream);
    hipMemsetAsync(bpad, 0, (size_t)20 * 66 * 2304 * 2, stream);

    repack_w<9><<<(512 * 1024 + 255) / 256, 256, 0, stream>>>(conv1_w, wb1, 512, 1024);
    repack_w<9><<<(256 * 512 + 255) / 256, 256, 0, stream>>>(conv2_w, wb2, 256, 512);
    bn_fold<<<2, 256, 0, stream>>>(bn1_g, bn1_b, bn1_m, bn1_v, s1, t1, 512);
    bn_fold<<<1, 256, 0, stream>>>(bn2_g, bn2_b, bn2_m, bn2_v, s2, t2, 256);
    setup_rowbase<<<(9856 + 255) / 256, 256, 0, stream>>>(rb1, rb2, rb1d, rbfc, pidx);

    transpose_fmap<<<dim3(7, 32, 64), dim3(32, 8), 0, stream>>>(fmap, fml);
    roi_kernel2<<<1088, 128, 0, stream>>>(fml, boxes, apad1);

    // conv1: M=9792 N=512 K=9216, 128x128 tile, split-K x3 -> 924 blocks
    gemm_k<0, 3><<<dim3(4, 77, 3), 256, 0, stream>>>(apad1, rb1, wb1, part1);
    reduce_k<3><<<(9792 * 512 + 255) / 256, 256, 0, stream>>>(part1, apad2, s1, t1);

    // prep overlaying dead apad1 (after conv1)
    repack_w<3><<<(2304 * 2304 + 255) / 256, 256, 0, stream>>>(conv1d_w, wb1d, 2304, 2304);
    transpose_fc1<<<dim3(72, 32), dim3(32, 8), 0, stream>>>(fc1_w, fc1t);
    transpose_w2<<<(30 * 1024 + 255) / 256, 256, 0, stream>>>(fc2_w, w2t);

    // conv2: M=9792 N=256 K=4608, split-K x6 -> 924 blocks
    gemm_k<1, 6><<<dim3(2, 77, 6), 256, 0, stream>>>(apad2, rb2, wb2, part2);
    reduce_k<0><<<(9792 * 256 + 255) / 256, 256, 0, stream>>>(part2, feat, s2, t2);
    assemble<<<dim3(64, 20), 256, 0, stream>>>(feat, pidx, bpad);
    // conv1d: M=1280 N=2304 K=6912, split-K x4 -> 720 blocks
    gemm_k<2, 4><<<dim3(18, 10, 4), 256, 0, stream>>>(bpad, rb1d, wb1d, part1d);
    reduce_k<1><<<(1280 * 2304 + 255) / 256, 256, 0, stream>>>(part1d, xbuf, conv1d_b, nullptr);
    // fc1: M=1024 N=1024 K=2304, split-K x6 -> 384 blocks
    gemm_k<3, 6><<<dim3(8, 8, 6), 256, 0, stream>>>(xbuf, rbfc, fc1t, partfc);
    reduce_k<2><<<(1024 * 1024 + 255) / 256, 256, 0, stream>>>(partfc, hbuf, fc1_b, nullptr);
    fc2_kernel<<<128, 256, 0, stream>>>(hbuf, w2t, fc2_b, out);
    (void)in_sizes; (void)n_in; (void)out_size; (void)ws_size;
}

// Round 6
// 591.074 us; speedup vs baseline: 2.1664x; 1.0551x over previous
//
#include <hip/hip_runtime.h>
#include <hip/hip_bf16.h>
#include <cstdint>
#include <cstddef>

typedef __bf16 bf16;
typedef __bf16 bf16x8 __attribute__((ext_vector_type(8)));
typedef float f32x4 __attribute__((ext_vector_type(4)));

// async global->LDS DMA, 16B per lane; lds dest wave-uniform base + lane*16
__device__ __forceinline__ void gload_lds16(const bf16* g, bf16* l) {
    __builtin_amdgcn_global_load_lds((const __attribute__((address_space(1))) void*)g,
                                     (__attribute__((address_space(3))) void*)l, 16, 0, 0);
}

// ---------------- weight repack (coalesced): w[OC][IC][NT] -> out[OC][NT*IC] bf16
template <int NT>
__global__ void __launch_bounds__(256) repack_w(const float* __restrict__ w, bf16* __restrict__ out,
                                                int OC, int IC) {
    int idx = blockIdx.x * 256 + threadIdx.x;
    if (idx >= OC * IC) return;
    int oc = idx / IC;
    int ic = idx - oc * IC;
    const float* src = w + (size_t)idx * NT;
    #pragma unroll
    for (int t = 0; t < NT; t++)
        out[(size_t)oc * NT * IC + t * IC + ic] = (bf16)src[t];
}

// ---------------- fc1_w [2304][1024] -> fc1t [1024][2304] bf16 (LDS tiled)
__global__ void __launch_bounds__(256) transpose_fc1(const float* __restrict__ w, bf16* __restrict__ out) {
    __shared__ float t[32][33];
    int iT = blockIdx.x * 32;
    int oT = blockIdx.y * 32;
    int tx = threadIdx.x, ty = threadIdx.y;   // 32 x 8
    #pragma unroll
    for (int j = 0; j < 4; j++)
        t[ty + j * 8][tx] = w[(size_t)(iT + ty + j * 8) * 1024 + oT + tx];
    __syncthreads();
    #pragma unroll
    for (int j = 0; j < 4; j++)
        out[(size_t)(oT + ty + j * 8) * 2304 + iT + tx] = (bf16)t[tx][ty + j * 8];
}

// ---------------- fc2_w [1024][30] -> w2t [30][1024] bf16 (tiny)
__global__ void __launch_bounds__(256) transpose_w2(const float* __restrict__ w, bf16* __restrict__ out) {
    int idx = blockIdx.x * 256 + threadIdx.x;
    if (idx >= 30 * 1024) return;
    int n = idx / 1024, k = idx - n * 1024;
    out[idx] = (bf16)w[(size_t)k * 30 + n];
}

// ---------------- BN fold
__global__ void __launch_bounds__(256) bn_fold(const float* __restrict__ g, const float* __restrict__ b,
                                               const float* __restrict__ m, const float* __restrict__ v,
                                               float* __restrict__ s, float* __restrict__ t, int n) {
    int i = blockIdx.x * 256 + threadIdx.x;
    if (i >= n) return;
    float sc = g[i] * rsqrtf(v[i] + 1e-5f);
    s[i] = sc;
    t[i] = b[i] - m[i] * sc;
}

// ---------------- rowbase arrays
__global__ void __launch_bounds__(256) setup_rowbase(int* __restrict__ rb1, int* __restrict__ rb2,
                                                     int* __restrict__ rb1d, int* __restrict__ rbfc,
                                                     const int* __restrict__ pidx) {
    int m = blockIdx.x * 256 + threadIdx.x;
    if (m < 9856) {
        int mm = m < 9792 ? m : 0;
        int img = mm / 9, pos = mm - img * 9;
        int base = img * 25 + (pos / 3) * 5 + (pos % 3);
        rb1[m] = base * 1024;
        rb2[m] = base * 512;
    }
    if (m < 1280) {
        int p = m >> 6, t = m & 63;
        rb1d[m] = (p * 66 + t) * 2304;
    }
    if (m < 1024) {
        int b = m >> 4;
        rbfc[m] = (b * 20 + pidx[m]) * 2304;
    }
}

// ---------------- fmap transpose to channels-last bf16
__global__ void __launch_bounds__(256) transpose_fmap(const float* __restrict__ fmap, bf16* __restrict__ fml) {
    __shared__ float t[32][33];
    int img = blockIdx.z;
    int hwT = blockIdx.x * 32;
    int cT  = blockIdx.y * 32;
    int tx = threadIdx.x, ty = threadIdx.y;
    #pragma unroll
    for (int j = 0; j < 4; j++) {
        int c = cT + ty + j * 8;
        int hw = hwT + tx;
        if (hw < 196)
            t[ty + j * 8][tx] = fmap[((size_t)img * 1024 + c) * 196 + hw];
    }
    __syncthreads();
    #pragma unroll
    for (int j = 0; j < 4; j++) {
        int hw = hwT + ty + j * 8;
        int c = cT + tx;
        if (hw < 196)
            fml[((size_t)img * 196 + hw) * 1024 + c] = (bf16)t[tx][ty + j * 8];
    }
}

// ---------------- roi_align (channels-last) -> apad1 interior
__global__ void __launch_bounds__(128) roi_kernel2(const bf16* __restrict__ fml, const float* __restrict__ boxes,
                                                   bf16* __restrict__ apad) {
    int box = blockIdx.x;
    int tid = threadIdx.x;
    float x1, y1, x2, y2;
    int img;
    if (box < 64) { img = box; x1 = 0.f; y1 = 0.f; x2 = 14.f; y2 = 14.f; }
    else {
        int ib = box - 64;
        img = ib >> 4;
        const float* bb = boxes + (size_t)ib * 4;
        x1 = bb[0]; y1 = bb[1]; x2 = bb[2]; y2 = bb[3];
    }
    float rw = fmaxf(x2 - x1, 1.f), rh = fmaxf(y2 - y1, 1.f);
    __shared__ float swy[6], swx[6];
    __shared__ int sy0[6], sx0[6];
    if (tid < 6) {
        int i = tid;
        float pos = ((float)i + 0.5f) * 0.5f;
        float yv = fminf(fmaxf(y1 + pos * (rh * (1.f / 3.f)), 0.f), 13.f);
        float y0 = floorf(yv);
        sy0[i] = (int)y0; swy[i] = yv - y0;
        float xv = fminf(fmaxf(x1 + pos * (rw * (1.f / 3.f)), 0.f), 13.f);
        float x0 = floorf(xv);
        sx0[i] = (int)x0; swx[i] = xv - x0;
    }
    __syncthreads();
    const bf16* base = fml + (size_t)img * 196 * 1024 + tid * 8;
    #pragma unroll
    for (int oy = 0; oy < 3; oy++) {
        #pragma unroll
        for (int ox = 0; ox < 3; ox++) {
            float acc[8];
            #pragma unroll
            for (int e = 0; e < 8; e++) acc[e] = 0.f;
            #pragma unroll
            for (int dy = 0; dy < 2; dy++) {
                int sy = 2 * oy + dy;
                int y0 = sy0[sy]; float wy = swy[sy];
                int y1i = min(y0 + 1, 13);
                #pragma unroll
                for (int dx = 0; dx < 2; dx++) {
                    int sx = 2 * ox + dx;
                    int x0 = sx0[sx]; float wx = swx[sx];
                    int x1i = min(x0 + 1, 13);
                    bf16x8 f00 = *(const bf16x8*)(base + (size_t)(y0 * 14 + x0) * 1024);
                    bf16x8 f01 = *(const bf16x8*)(base + (size_t)(y0 * 14 + x1i) * 1024);
                    bf16x8 f10 = *(const bf16x8*)(base + (size_t)(y1i * 14 + x0) * 1024);
                    bf16x8 f11 = *(const bf16x8*)(base + (size_t)(y1i * 14 + x1i) * 1024);
                    float w00 = (1.f - wy) * (1.f - wx), w01 = (1.f - wy) * wx;
                    float w10 = wy * (1.f - wx),         w11 = wy * wx;
                    #pragma unroll
                    for (int e = 0; e < 8; e++)
                        acc[e] += w00 * (float)f00[e] + w01 * (float)f01[e]
                                + w10 * (float)f10[e] + w11 * (float)f11[e];
                }
            }
            bf16x8 o;
            #pragma unroll
            for (int e = 0; e < 8; e++) o[e] = (bf16)(acc[e] * 0.25f);
            *(bf16x8*)(apad + ((size_t)box * 25 + (oy + 1) * 5 + (ox + 1)) * 1024 + tid * 8) = o;
        }
    }
}

// ---------------- behavior assembly
__global__ void __launch_bounds__(256) assemble(const float* __restrict__ feat, const int* __restrict__ pidx,
                                                bf16* __restrict__ bpad) {
    int b = blockIdx.x;
    int p = blockIdx.y;
    __shared__ int idxs[16];
    if (threadIdx.x < 16) idxs[threadIdx.x] = pidx[b * 16 + threadIdx.x];
    __syncthreads();
    const float* g = feat + (size_t)b * 2304;
    for (int f = threadIdx.x; f < 2304; f += 256) {
        float v = g[f];
        #pragma unroll
        for (int n = 0; n < 16; n++)
            if (idxs[n] == p) v += feat[(size_t)(64 + b * 16 + n) * 2304 + f];
        bpad[((size_t)p * 66 + (b + 1)) * 2304 + f] = (bf16)v;
    }
}

// ---------------- implicit-GEMM MFMA: 128x128 tile, global_load_lds staging + XOR swizzle
// 4 waves in 2x2; wave = 64x64 (4x4 16x16x32 tiles, acc[4][4]); BK=64.
// LDS [row][64], but lane (sr=l>>3, c3=l&7) stages global chunk (c3^sr) -> LDS[row][c]
// holds chunk c^(row&7). Readers XOR column with (ln16&7): conflict-free (2-way floor).
// All modes write fp32 partials part[z][M][N]; reducers fuse epilogues.
template <int MODE, int NSPLIT>
__global__ void __launch_bounds__(256) gemm_k(const bf16* __restrict__ A, const int* __restrict__ rowbase,
                                              const bf16* __restrict__ Bw, float* __restrict__ outp) {
    constexpr int K   = MODE == 0 ? 9216 : MODE == 1 ? 4608 : MODE == 2 ? 6912 : 2304;
    constexpr int N   = MODE == 0 ? 512  : MODE == 1 ? 256  : MODE == 2 ? 2304 : 1024;
    constexpr int Cin = MODE == 0 ? 1024 : MODE == 1 ? 512  : 2304;
    constexpr int M   = MODE <= 1 ? 9792 : MODE == 2 ? 1280 : 1024;
    constexpr bool C3 = (MODE <= 1);
    constexpr bool MPAD = (M % 128) != 0;
    constexpr int KTS = (K / 64) / NSPLIT;

    const int bm = blockIdx.y * 128;
    const int bn = blockIdx.x * 128;
    const int z  = blockIdx.z;
    const int tid = threadIdx.x;
    const int lane = tid & 63, wave = tid >> 6;
    const int q = lane >> 4, ln16 = lane & 15;
    const int wr = wave >> 1, wc = wave & 1;

    __shared__ __align__(16) bf16 As[128 * 64];
    __shared__ __align__(16) bf16 Bs[128 * 64];

    // staging: wave w stages As/Bs rows [w*32, w*32+32), 4 instrs x 8 rows x 1024B.
    // lane: row += sr, fetches global chunk (c3 ^ sr) -> swizzled LDS layout.
    const int sr = lane >> 3;
    const int sc = ((lane & 7) ^ sr) * 8;    // XOR-permuted chunk offset (elems)
    int rbA[4];
    const bf16* gB[4];
    #pragma unroll
    for (int u = 0; u < 4; u++) {
        int row = wave * 32 + u * 8 + sr;
        rbA[u] = rowbase[bm + row];
        gB[u] = Bw + (size_t)(bn + row) * K + sc;
    }

    f32x4 acc[4][4];
    #pragma unroll
    for (int mt = 0; mt < 4; mt++)
        #pragma unroll
        for (int nt = 0; nt < 4; nt++)
            acc[mt][nt] = (f32x4){0.f, 0.f, 0.f, 0.f};

    for (int kt = z * KTS; kt < z * KTS + KTS; kt++) {
        const int k0 = kt * 64;
        const int tap = k0 / Cin;
        const int inner = k0 - tap * Cin;
        const int poff = C3 ? ((tap / 3) * 5 + (tap % 3)) : tap;
        const int aoff = poff * Cin + inner + sc;

        __syncthreads();   // all waves done reading previous tile
        #pragma unroll
        for (int u = 0; u < 4; u++)
            gload_lds16(A + (size_t)(rbA[u] + aoff), As + (wave * 32 + u * 8) * 64);
        #pragma unroll
        for (int u = 0; u < 4; u++)
            gload_lds16(gB[u] + k0, Bs + (wave * 32 + u * 8) * 64);
        __syncthreads();   // drains vmcnt -> staged data visible

        #pragma unroll
        for (int s = 0; s < 2; s++) {
            bf16x8 af[4], bfr[4];
            #pragma unroll
            for (int mt = 0; mt < 4; mt++) {
                int r = wr * 64 + mt * 16 + ln16;
                af[mt] = *(const bf16x8*)(As + r * 64 + (((4 * s + q) ^ (ln16 & 7)) << 3));
            }
            #pragma unroll
            for (int nt = 0; nt < 4; nt++) {
                int r = wc * 64 + nt * 16 + ln16;
                bfr[nt] = *(const bf16x8*)(Bs + r * 64 + (((4 * s + q) ^ (ln16 & 7)) << 3));
            }
            #pragma unroll
            for (int mt = 0; mt < 4; mt++)
                #pragma unroll
                for (int nt = 0; nt < 4; nt++)
                    acc[mt][nt] = __builtin_amdgcn_mfma_f32_16x16x32_bf16(af[mt], bfr[nt], acc[mt][nt], 0, 0, 0);
        }
    }

    // epilogue: C/D layout col=lane&15, row=quad*4+reg; fp32 partials
    #pragma unroll
    for (int mt = 0; mt < 4; mt++) {
        int gmBase = bm + wr * 64 + mt * 16 + q * 4;
        #pragma unroll
        for (int r = 0; r < 4; r++) {
            int gm = gmBase + r;
            if (MPAD && gm >= M) continue;
            #pragma unroll
            for (int nt = 0; nt < 4; nt++) {
                int gn = bn + wc * 64 + nt * 16 + ln16;
                outp[((size_t)z * M + gm) * N + gn] = acc[mt][nt][r];
            }
        }
    }
}

// ---------------- split-K reducers
// RMODE 0: conv2 -> feat fp32 (BN+leaky, scatter [img][oc*9+pos]), S=6
// RMODE 1: conv1d -> xbuf bf16 (+bias, [t][p][oc]), S=4
// RMODE 2: fc1 -> hbuf bf16 (+bias, relu), S=6
// RMODE 3: conv1 -> apad2 bf16 interior (BN+leaky), S=3
template <int RMODE>
__global__ void __launch_bounds__(256) reduce_k(const float* __restrict__ part, void* __restrict__ outp,
                                                const float* __restrict__ c0, const float* __restrict__ c1) {
    constexpr int M = RMODE == 0 ? 9792 : RMODE == 1 ? 1280 : RMODE == 2 ? 1024 : 9792;
    constexpr int N = RMODE == 0 ? 256  : RMODE == 1 ? 2304 : RMODE == 2 ? 1024 : 512;
    constexpr int S = RMODE == 0 ? 6    : RMODE == 1 ? 4    : RMODE == 2 ? 6    : 3;
    int idx = blockIdx.x * 256 + threadIdx.x;
    if (idx >= M * N) return;
    int m = idx / N, n = idx - m * N;
    float v = 0.f;
    #pragma unroll
    for (int s = 0; s < S; s++) v += part[(size_t)s * M * N + idx];
    if constexpr (RMODE == 0) {
        v = v * c0[n] + c1[n];
        v = v > 0.f ? v : 0.1f * v;
        int img = m / 9, pos = m - img * 9;
        ((float*)outp)[(size_t)img * 2304 + n * 9 + pos] = v;
    } else if constexpr (RMODE == 1) {
        v += c0[n];
        int p = m >> 6, t = m & 63;
        ((bf16*)outp)[((size_t)t * 20 + p) * 2304 + n] = (bf16)v;
    } else if constexpr (RMODE == 2) {
        v = fmaxf(v + c0[n], 0.f);
        ((bf16*)outp)[idx] = (bf16)v;
    } else {
        v = v * c0[n] + c1[n];
        v = v > 0.f ? v : 0.1f * v;
        int img = m / 9, pos = m - img * 9;
        ((bf16*)outp)[(size_t)(img * 25 + (pos / 3 + 1) * 5 + (pos % 3 + 1)) * 512 + n] = (bf16)v;
    }
}

// ---------------- fc2
__global__ void __launch_bounds__(256) fc2_kernel(const bf16* __restrict__ h, const bf16* __restrict__ w2t,
                                                  const float* __restrict__ b2, float* __restrict__ out) {
    int tid = threadIdx.x;
    int m = blockIdx.x * 8 + (tid >> 5);
    int n = tid & 31;
    int n2 = n < 30 ? n : 29;
    const bf16* hr = h + (size_t)m * 1024;
    const bf16* wr = w2t + (size_t)n2 * 1024;
    float acc = 0.f;
    for (int k = 0; k < 1024; k += 8) {
        bf16x8 hv = *(const bf16x8*)(hr + k);
        bf16x8 wv = *(const bf16x8*)(wr + k);
        #pragma unroll
        for (int e = 0; e < 8; e++) acc += (float)hv[e] * (float)wv[e];
    }
    if (n < 30) out[(size_t)m * 30 + n] = acc + b2[n];
}

extern "C" void kernel_launch(void* const* d_in, const int* in_sizes, int n_in,
                              void* d_out, int out_size, void* d_ws, size_t ws_size,
                              hipStream_t stream) {
    const float* fmap     = (const float*)d_in[0];
    const float* boxes    = (const float*)d_in[1];
    const int*   pidx     = (const int*)d_in[2];
    const float* conv1_w  = (const float*)d_in[3];
    const float* bn1_g    = (const float*)d_in[4];
    const float* bn1_b    = (const float*)d_in[5];
    const float* bn1_m    = (const float*)d_in[6];
    const float* bn1_v    = (const float*)d_in[7];
    const float* conv2_w  = (const float*)d_in[8];
    const float* bn2_g    = (const float*)d_in[9];
    const float* bn2_b    = (const float*)d_in[10];
    const float* bn2_m    = (const float*)d_in[11];
    const float* bn2_v    = (const float*)d_in[12];
    const float* conv1d_w = (const float*)d_in[13];
    const float* conv1d_b = (const float*)d_in[14];
    const float* fc1_w    = (const float*)d_in[15];
    const float* fc1_b    = (const float*)d_in[16];
    const float* fc2_w    = (const float*)d_in[17];
    const float* fc2_b    = (const float*)d_in[18];
    float* out = (float*)d_out;

    char* ws = (char*)d_ws;

    // ---- exact-lifetime arena (peak 171.7 MB) ----
    float* s1   = (float*)(ws + 0);
    float* t1   = (float*)(ws + 2048);
    float* s2   = (float*)(ws + 4096);
    float* t2   = (float*)(ws + 5120);
    int*   rb1  = (int*)(ws + 6144);
    int*   rb2  = (int*)(ws + 45568);
    int*   rb1d = (int*)(ws + 84992);
    int*   rbfc = (int*)(ws + 90112);
    // R_A rotating @ [98304, 60260352): fml -> part1 -> part2 -> part1d -> partfc
    bf16*  fml    = (bf16*)(ws + 98304);
    float* part1  = (float*)(ws + 98304);   // 3 x 9792 x 512 x 4 = 60162048 (exact fit)
    float* part2  = (float*)(ws + 98304);   // 6 x 9792 x 256 x 4 = 60162048 (exact fit)
    float* part1d = (float*)(ws + 98304);   // 4 x 1280 x 2304 x 4 = 47.2 MB
    float* partfc = (float*)(ws + 98304);   // 6 x 1024 x 1024 x 4 = 25.2 MB
    // R_B @ [60260352, ...): apad1 (roi->conv1), then overlaid after conv1:
    bf16*  apad1  = (bf16*)(ws + 60260352);     // 55.71 MB
    bf16*  wb1d   = (bf16*)(ws + 60260352);     // 31.85 MB
    bf16*  fc1t   = (bf16*)(ws + 92110848);
    bf16*  xbuf   = (bf16*)(ws + 96829440);
    bf16*  hbuf   = (bf16*)(ws + 102727680);
    bf16*  w2t    = (bf16*)(ws + 104824832);
    // dedicated
    bf16*  wb1    = (bf16*)(ws + 115965952);
    bf16*  wb2    = (bf16*)(ws + 125403136);
    bf16*  apad2  = (bf16*)(ws + 127762432);
    float* feat   = (float*)(ws + 155615232);
    bf16*  bpad   = (bf16*)(ws + 165642240);

    hipMemsetAsync(apad1, 0, (size_t)1088 * 25 * 1024 * 2, stream);
    hipMemsetAsync(apad2, 0, (size_t)1088 * 25 * 512 * 2, stream);
    hipMemsetAsync(bpad, 0, (size_t)20 * 66 * 2304 * 2, stream);

    repack_w<9><<<(512 * 1024 + 255) / 256, 256, 0, stream>>>(conv1_w, wb1, 512, 1024);
    repack_w<9><<<(256 * 512 + 255) / 256, 256, 0, stream>>>(conv2_w, wb2, 256, 512);
    bn_fold<<<2, 256, 0, stream>>>(bn1_g, bn1_b, bn1_m, bn1_v, s1, t1, 512);
    bn_fold<<<1, 256, 0, stream>>>(bn2_g, bn2_b, bn2_m, bn2_v, s2, t2, 256);
    setup_rowbase<<<(9856 + 255) / 256, 256, 0, stream>>>(rb1, rb2, rb1d, rbfc, pidx);

    transpose_fmap<<<dim3(7, 32, 64), dim3(32, 8), 0, stream>>>(fmap, fml);
    roi_kernel2<<<1088, 128, 0, stream>>>(fml, boxes, apad1);

    // conv1: M=9792 N=512 K=9216, 128x128 tile, split-K x3 -> 924 blocks
    gemm_k<0, 3><<<dim3(4, 77, 3), 256, 0, stream>>>(apad1, rb1, wb1, part1);
    reduce_k<3><<<(9792 * 512 + 255) / 256, 256, 0, stream>>>(part1, apad2, s1, t1);

    // prep overlaying dead apad1 (after conv1)
    repack_w<3><<<(2304 * 2304 + 255) / 256, 256, 0, stream>>>(conv1d_w, wb1d, 2304, 2304);
    transpose_fc1<<<dim3(72, 32), dim3(32, 8), 0, stream>>>(fc1_w, fc1t);
    transpose_w2<<<(30 * 1024 + 255) / 256, 256, 0, stream>>>(fc2_w, w2t);

    // conv2: M=9792 N=256 K=4608, split-K x6 -> 924 blocks
    gemm_k<1, 6><<<dim3(2, 77, 6), 256, 0, stream>>>(apad2, rb2, wb2, part2);
    reduce_k<0><<<(9792 * 256 + 255) / 256, 256, 0, stream>>>(part2, feat, s2, t2);
    assemble<<<dim3(64, 20), 256, 0, stream>>>(feat, pidx, bpad);
    // conv1d: M=1280 N=2304 K=6912, split-K x4 -> 720 blocks
    gemm_k<2, 4><<<dim3(18, 10, 4), 256, 0, stream>>>(bpad, rb1d, wb1d, part1d);
    reduce_k<1><<<(1280 * 2304 + 255) / 256, 256, 0, stream>>>(part1d, xbuf, conv1d_b, nullptr);
    // fc1: M=1024 N=1024 K=2304, split-K x6 -> 384 blocks
    gemm_k<3, 6><<<dim3(8, 8, 6), 256, 0, stream>>>(xbuf, rbfc, fc1t, partfc);
    reduce_k<2><<<(1024 * 1024 + 255) / 256, 256, 0, stream>>>(partfc, hbuf, fc1_b, nullptr);
    fc2_kernel<<<128, 256, 0, stream>>>(hbuf, w2t, fc2_b, out);
    (void)in_sizes; (void)n_in; (void)out_size; (void)ws_size;
}

// Round 7
// 502.903 us; speedup vs baseline: 2.5463x; 1.1753x over previous
//
#include <hip/hip_runtime.h>
#include <hip/hip_bf16.h>
#include <cstdint>
#include <cstddef>

typedef __bf16 bf16;
typedef __bf16 bf16x8 __attribute__((ext_vector_type(8)));
typedef float f32x4 __attribute__((ext_vector_type(4)));

// async global->LDS DMA, 16B per lane; lds dest wave-uniform base + lane*16
__device__ __forceinline__ void gload_lds16(const bf16* g, bf16* l) {
    __builtin_amdgcn_global_load_lds((const __attribute__((address_space(1))) void*)g,
                                     (__attribute__((address_space(3))) void*)l, 16, 0, 0);
}

// ---------------- weight repack (coalesced): w[OC][IC][NT] -> out[OC][NT*IC] bf16
template <int NT>
__global__ void __launch_bounds__(256) repack_w(const float* __restrict__ w, bf16* __restrict__ out,
                                                int OC, int IC) {
    int idx = blockIdx.x * 256 + threadIdx.x;
    if (idx >= OC * IC) return;
    int oc = idx / IC;
    int ic = idx - oc * IC;
    const float* src = w + (size_t)idx * NT;
    #pragma unroll
    for (int t = 0; t < NT; t++)
        out[(size_t)oc * NT * IC + t * IC + ic] = (bf16)src[t];
}

// ---------------- fc1_w [2304][1024] -> fc1t [1024][2304] bf16 (LDS tiled)
__global__ void __launch_bounds__(256) transpose_fc1(const float* __restrict__ w, bf16* __restrict__ out) {
    __shared__ float t[32][33];
    int iT = blockIdx.x * 32;
    int oT = blockIdx.y * 32;
    int tx = threadIdx.x, ty = threadIdx.y;   // 32 x 8
    #pragma unroll
    for (int j = 0; j < 4; j++)
        t[ty + j * 8][tx] = w[(size_t)(iT + ty + j * 8) * 1024 + oT + tx];
    __syncthreads();
    #pragma unroll
    for (int j = 0; j < 4; j++)
        out[(size_t)(oT + ty + j * 8) * 2304 + iT + tx] = (bf16)t[tx][ty + j * 8];
}

// ---------------- fc2_w [1024][30] -> w2t [30][1024] bf16 (tiny)
__global__ void __launch_bounds__(256) transpose_w2(const float* __restrict__ w, bf16* __restrict__ out) {
    int idx = blockIdx.x * 256 + threadIdx.x;
    if (idx >= 30 * 1024) return;
    int n = idx / 1024, k = idx - n * 1024;
    out[idx] = (bf16)w[(size_t)k * 30 + n];
}

// ---------------- unified setup: per-tap rowbase tables, zero pages, BN folds
// rb1t/rb2t[9][9856]: conv1/conv2 taps (3x3 over 3x3 grid, invalid -> 0 = zero page)
// rb1dt[3][1280]: conv1d taps over t in [0,64)
// rbfc[1024]: fc1 person gather
__global__ void __launch_bounds__(256) setup_all(int* __restrict__ rb1t, int* __restrict__ rb2t,
                                                 int* __restrict__ rb1dt, int* __restrict__ rbfc,
                                                 const int* __restrict__ pidx,
                                                 bf16* __restrict__ zp1, bf16* __restrict__ zp2,
                                                 bf16* __restrict__ zp3,
                                                 const float* g1, const float* b1, const float* m1, const float* v1,
                                                 const float* g2, const float* b2, const float* m2, const float* v2,
                                                 float* __restrict__ s1, float* __restrict__ t1,
                                                 float* __restrict__ s2, float* __restrict__ t2) {
    int m = blockIdx.x * 256 + threadIdx.x;
    if (m < 9 * 9856) {
        int tap = m / 9856, r = m - tap * 9856;
        int mm = r < 9792 ? r : 0;
        int img = mm / 9, pos = mm - img * 9;
        int oy = pos / 3, ox = pos - oy * 3;
        int ty = tap / 3, tx = tap - ty * 3;
        int iy = oy + ty - 1, ix = ox + tx - 1;
        bool valid = (iy >= 0) & (iy < 3) & (ix >= 0) & (ix < 3);
        int cell = img * 9 + iy * 3 + ix;
        rb1t[m] = valid ? 1024 + cell * 1024 : 0;
        rb2t[m] = valid ? 512 + cell * 512 : 0;
    }
    if (m < 3 * 1280) {
        int tap = m / 1280, r = m - tap * 1280;
        int p = r >> 6, t = r & 63;
        int tt = t + tap - 1;
        bool valid = (tt >= 0) & (tt < 64);
        rb1dt[m] = valid ? 2304 + (p * 64 + tt) * 2304 : 0;
    }
    if (m < 1024) {
        int b = m >> 4;
        rbfc[m] = (b * 20 + pidx[m]) * 2304;
    }
    if (m < 1024) zp1[m] = (bf16)0.f;
    if (m < 512)  zp2[m] = (bf16)0.f;
    if (m < 2304) zp3[m] = (bf16)0.f;
    if (m < 512) {
        float sc = g1[m] * rsqrtf(v1[m] + 1e-5f);
        s1[m] = sc; t1[m] = b1[m] - m1[m] * sc;
    } else if (m < 768) {
        int i = m - 512;
        float sc = g2[i] * rsqrtf(v2[i] + 1e-5f);
        s2[i] = sc; t2[i] = b2[i] - m2[i] * sc;
    }
}

// ---------------- fmap transpose to channels-last bf16
__global__ void __launch_bounds__(256) transpose_fmap(const float* __restrict__ fmap, bf16* __restrict__ fml) {
    __shared__ float t[32][33];
    int img = blockIdx.z;
    int hwT = blockIdx.x * 32;
    int cT  = blockIdx.y * 32;
    int tx = threadIdx.x, ty = threadIdx.y;
    #pragma unroll
    for (int j = 0; j < 4; j++) {
        int c = cT + ty + j * 8;
        int hw = hwT + tx;
        if (hw < 196)
            t[ty + j * 8][tx] = fmap[((size_t)img * 1024 + c) * 196 + hw];
    }
    __syncthreads();
    #pragma unroll
    for (int j = 0; j < 4; j++) {
        int hw = hwT + ty + j * 8;
        int c = cT + tx;
        if (hw < 196)
            fml[((size_t)img * 196 + hw) * 1024 + c] = (bf16)t[tx][ty + j * 8];
    }
}

// ---------------- roi_align (channels-last) -> a1c compact [1088][9][1024] (after 1024-elem zp)
__global__ void __launch_bounds__(128) roi_kernel2(const bf16* __restrict__ fml, const float* __restrict__ boxes,
                                                   bf16* __restrict__ a1c) {
    int box = blockIdx.x;
    int tid = threadIdx.x;
    float x1, y1, x2, y2;
    int img;
    if (box < 64) { img = box; x1 = 0.f; y1 = 0.f; x2 = 14.f; y2 = 14.f; }
    else {
        int ib = box - 64;
        img = ib >> 4;
        const float* bb = boxes + (size_t)ib * 4;
        x1 = bb[0]; y1 = bb[1]; x2 = bb[2]; y2 = bb[3];
    }
    float rw = fmaxf(x2 - x1, 1.f), rh = fmaxf(y2 - y1, 1.f);
    __shared__ float swy[6], swx[6];
    __shared__ int sy0[6], sx0[6];
    if (tid < 6) {
        int i = tid;
        float pos = ((float)i + 0.5f) * 0.5f;
        float yv = fminf(fmaxf(y1 + pos * (rh * (1.f / 3.f)), 0.f), 13.f);
        float y0 = floorf(yv);
        sy0[i] = (int)y0; swy[i] = yv - y0;
        float xv = fminf(fmaxf(x1 + pos * (rw * (1.f / 3.f)), 0.f), 13.f);
        float x0 = floorf(xv);
        sx0[i] = (int)x0; swx[i] = xv - x0;
    }
    __syncthreads();
    const bf16* base = fml + (size_t)img * 196 * 1024 + tid * 8;
    #pragma unroll
    for (int oy = 0; oy < 3; oy++) {
        #pragma unroll
        for (int ox = 0; ox < 3; ox++) {
            float acc[8];
            #pragma unroll
            for (int e = 0; e < 8; e++) acc[e] = 0.f;
            #pragma unroll
            for (int dy = 0; dy < 2; dy++) {
                int sy = 2 * oy + dy;
                int y0 = sy0[sy]; float wy = swy[sy];
                int y1i = min(y0 + 1, 13);
                #pragma unroll
                for (int dx = 0; dx < 2; dx++) {
                    int sx = 2 * ox + dx;
                    int x0 = sx0[sx]; float wx = swx[sx];
                    int x1i = min(x0 + 1, 13);
                    bf16x8 f00 = *(const bf16x8*)(base + (size_t)(y0 * 14 + x0) * 1024);
                    bf16x8 f01 = *(const bf16x8*)(base + (size_t)(y0 * 14 + x1i) * 1024);
                    bf16x8 f10 = *(const bf16x8*)(base + (size_t)(y1i * 14 + x0) * 1024);
                    bf16x8 f11 = *(const bf16x8*)(base + (size_t)(y1i * 14 + x1i) * 1024);
                    float w00 = (1.f - wy) * (1.f - wx), w01 = (1.f - wy) * wx;
                    float w10 = wy * (1.f - wx),         w11 = wy * wx;
                    #pragma unroll
                    for (int e = 0; e < 8; e++)
                        acc[e] += w00 * (float)f00[e] + w01 * (float)f01[e]
                                + w10 * (float)f10[e] + w11 * (float)f11[e];
                }
            }
            bf16x8 o;
            #pragma unroll
            for (int e = 0; e < 8; e++) o[e] = (bf16)(acc[e] * 0.25f);
            *(bf16x8*)(a1c + 1024 + ((size_t)box * 9 + oy * 3 + ox) * 1024 + tid * 8) = o;
        }
    }
}

// ---------------- behavior assembly -> asm3 compact [20][64][2304] (after 2304-elem zp)
__global__ void __launch_bounds__(256) assemble(const float* __restrict__ feat, const int* __restrict__ pidx,
                                                bf16* __restrict__ asm3) {
    int b = blockIdx.x;
    int p = blockIdx.y;
    __shared__ int idxs[16];
    if (threadIdx.x < 16) idxs[threadIdx.x] = pidx[b * 16 + threadIdx.x];
    __syncthreads();
    const float* g = feat + (size_t)b * 2304;
    for (int f = threadIdx.x; f < 2304; f += 256) {
        float v = g[f];
        #pragma unroll
        for (int n = 0; n < 16; n++)
            if (idxs[n] == p) v += feat[(size_t)(64 + b * 16 + n) * 2304 + f];
        asm3[2304 + ((size_t)p * 64 + b) * 2304 + f] = (bf16)v;
    }
}

// ---------------- implicit-GEMM MFMA: 128x128 tile, global_load_lds + XOR swizzle,
// per-tap row tables (zero rows -> zero page, no padded buffers).
// 4 waves 2x2; wave 64x64 (4x4 16x16x32, acc[4][4]); BK=64; split-K fp32 partials.
template <int MODE, int NSPLIT>
__global__ void __launch_bounds__(256) gemm_k(const bf16* __restrict__ A, const int* __restrict__ rowtab,
                                              const bf16* __restrict__ Bw, float* __restrict__ outp) {
    constexpr int K   = MODE == 0 ? 9216 : MODE == 1 ? 4608 : MODE == 2 ? 6912 : 2304;
    constexpr int N   = MODE == 0 ? 512  : MODE == 1 ? 256  : MODE == 2 ? 2304 : 1024;
    constexpr int Cin = MODE == 0 ? 1024 : MODE == 1 ? 512  : 2304;
    constexpr int M   = MODE <= 1 ? 9792 : MODE == 2 ? 1280 : 1024;
    constexpr int MT  = MODE <= 1 ? 9856 : MODE == 2 ? 1280 : 1024;   // table row stride
    constexpr bool MPAD = (M % 128) != 0;
    constexpr int KTS = (K / 64) / NSPLIT;

    const int bm = blockIdx.y * 128;
    const int bn = blockIdx.x * 128;
    const int z  = blockIdx.z;
    const int tid = threadIdx.x;
    const int lane = tid & 63, wave = tid >> 6;
    const int q = lane >> 4, ln16 = lane & 15;
    const int wr = wave >> 1, wc = wave & 1;

    __shared__ __align__(16) bf16 As[128 * 64];
    __shared__ __align__(16) bf16 Bs[128 * 64];

    const int sr = lane >> 3;
    const int sc = ((lane & 7) ^ sr) * 8;    // XOR-permuted chunk offset (elems)
    const bf16* gB[4];
    #pragma unroll
    for (int u = 0; u < 4; u++)
        gB[u] = Bw + (size_t)(bn + wave * 32 + u * 8 + sr) * K + sc;

    f32x4 acc[4][4];
    #pragma unroll
    for (int mt = 0; mt < 4; mt++)
        #pragma unroll
        for (int nt = 0; nt < 4; nt++)
            acc[mt][nt] = (f32x4){0.f, 0.f, 0.f, 0.f};

    int rbA[4];
    int curtap = -1;
    for (int kt = z * KTS; kt < z * KTS + KTS; kt++) {
        const int k0 = kt * 64;
        const int tap = k0 / Cin;                 // wave-uniform
        const int inner = k0 - tap * Cin;
        if (tap != curtap) {                      // few reloads per slice
            curtap = tap;
            #pragma unroll
            for (int u = 0; u < 4; u++)
                rbA[u] = rowtab[tap * MT + bm + wave * 32 + u * 8 + sr];
        }
        const int aoff = inner + sc;

        __syncthreads();   // all waves done reading previous tile
        #pragma unroll
        for (int u = 0; u < 4; u++)
            gload_lds16(A + (size_t)(rbA[u] + aoff), As + (wave * 32 + u * 8) * 64);
        #pragma unroll
        for (int u = 0; u < 4; u++)
            gload_lds16(gB[u] + k0, Bs + (wave * 32 + u * 8) * 64);
        __syncthreads();   // drains vmcnt -> staged data visible

        #pragma unroll
        for (int s = 0; s < 2; s++) {
            bf16x8 af[4], bfr[4];
            #pragma unroll
            for (int mt = 0; mt < 4; mt++) {
                int r = wr * 64 + mt * 16 + ln16;
                af[mt] = *(const bf16x8*)(As + r * 64 + (((4 * s + q) ^ (ln16 & 7)) << 3));
            }
            #pragma unroll
            for (int nt = 0; nt < 4; nt++) {
                int r = wc * 64 + nt * 16 + ln16;
                bfr[nt] = *(const bf16x8*)(Bs + r * 64 + (((4 * s + q) ^ (ln16 & 7)) << 3));
            }
            #pragma unroll
            for (int mt = 0; mt < 4; mt++)
                #pragma unroll
                for (int nt = 0; nt < 4; nt++)
                    acc[mt][nt] = __builtin_amdgcn_mfma_f32_16x16x32_bf16(af[mt], bfr[nt], acc[mt][nt], 0, 0, 0);
        }
    }

    // epilogue: C/D layout col=lane&15, row=quad*4+reg; fp32 partials
    #pragma unroll
    for (int mt = 0; mt < 4; mt++) {
        int gmBase = bm + wr * 64 + mt * 16 + q * 4;
        #pragma unroll
        for (int r = 0; r < 4; r++) {
            int gm = gmBase + r;
            if (MPAD && gm >= M) continue;
            #pragma unroll
            for (int nt = 0; nt < 4; nt++) {
                int gn = bn + wc * 64 + nt * 16 + ln16;
                outp[((size_t)z * M + gm) * N + gn] = acc[mt][nt][r];
            }
        }
    }
}

// ---------------- split-K reducers
// RMODE 0: conv2 -> feat fp32 (BN+leaky, scatter [img][oc*9+pos]), S=6
// RMODE 1: conv1d -> xbuf bf16 (+bias, [t][p][oc]), S=4
// RMODE 2: fc1 -> hbuf bf16 (+bias, relu), S=6
// RMODE 3: conv1 -> a2c compact bf16 (BN+leaky, linear +zp offset), S=3
template <int RMODE>
__global__ void __launch_bounds__(256) reduce_k(const float* __restrict__ part, void* __restrict__ outp,
                                                const float* __restrict__ c0, const float* __restrict__ c1) {
    constexpr int M = RMODE == 0 ? 9792 : RMODE == 1 ? 1280 : RMODE == 2 ? 1024 : 9792;
    constexpr int N = RMODE == 0 ? 256  : RMODE == 1 ? 2304 : RMODE == 2 ? 1024 : 512;
    constexpr int S = RMODE == 0 ? 6    : RMODE == 1 ? 4    : RMODE == 2 ? 6    : 3;
    int idx = blockIdx.x * 256 + threadIdx.x;
    if (idx >= M * N) return;
    int m = idx / N, n = idx - m * N;
    float v = 0.f;
    #pragma unroll
    for (int s = 0; s < S; s++) v += part[(size_t)s * M * N + idx];
    if constexpr (RMODE == 0) {
        v = v * c0[n] + c1[n];
        v = v > 0.f ? v : 0.1f * v;
        int img = m / 9, pos = m - img * 9;
        ((float*)outp)[(size_t)img * 2304 + n * 9 + pos] = v;
    } else if constexpr (RMODE == 1) {
        v += c0[n];
        int p = m >> 6, t = m & 63;
        ((bf16*)outp)[((size_t)t * 20 + p) * 2304 + n] = (bf16)v;
    } else if constexpr (RMODE == 2) {
        v = fmaxf(v + c0[n], 0.f);
        ((bf16*)outp)[idx] = (bf16)v;
    } else {
        v = v * c0[n] + c1[n];
        v = v > 0.f ? v : 0.1f * v;
        ((bf16*)outp)[512 + (size_t)m * 512 + n] = (bf16)v;   // compact, after zp2
    }
}

// ---------------- fc2
__global__ void __launch_bounds__(256) fc2_kernel(const bf16* __restrict__ h, const bf16* __restrict__ w2t,
                                                  const float* __restrict__ b2, float* __restrict__ out) {
    int tid = threadIdx.x;
    int m = blockIdx.x * 8 + (tid >> 5);
    int n = tid & 31;
    int n2 = n < 30 ? n : 29;
    const bf16* hr = h + (size_t)m * 1024;
    const bf16* wr = w2t + (size_t)n2 * 1024;
    float acc = 0.f;
    for (int k = 0; k < 1024; k += 8) {
        bf16x8 hv = *(const bf16x8*)(hr + k);
        bf16x8 wv = *(const bf16x8*)(wr + k);
        #pragma unroll
        for (int e = 0; e < 8; e++) acc += (float)hv[e] * (float)wv[e];
    }
    if (n < 30) out[(size_t)m * 30 + n] = acc + b2[n];
}

extern "C" void kernel_launch(void* const* d_in, const int* in_sizes, int n_in,
                              void* d_out, int out_size, void* d_ws, size_t ws_size,
                              hipStream_t stream) {
    const float* fmap     = (const float*)d_in[0];
    const float* boxes    = (const float*)d_in[1];
    const int*   pidx     = (const int*)d_in[2];
    const float* conv1_w  = (const float*)d_in[3];
    const float* bn1_g    = (const float*)d_in[4];
    const float* bn1_b    = (const float*)d_in[5];
    const float* bn1_m    = (const float*)d_in[6];
    const float* bn1_v    = (const float*)d_in[7];
    const float* conv2_w  = (const float*)d_in[8];
    const float* bn2_g    = (const float*)d_in[9];
    const float* bn2_b    = (const float*)d_in[10];
    const float* bn2_m    = (const float*)d_in[11];
    const float* bn2_v    = (const float*)d_in[12];
    const float* conv1d_w = (const float*)d_in[13];
    const float* conv1d_b = (const float*)d_in[14];
    const float* fc1_w    = (const float*)d_in[15];
    const float* fc1_b    = (const float*)d_in[16];
    const float* fc2_w    = (const float*)d_in[17];
    const float* fc2_b    = (const float*)d_in[18];
    float* out = (float*)d_out;

    char* ws = (char*)d_ws;

    // ---- arena (peak ~143.3 MB; prior proven >= 171.7 MB) ----
    float* s1    = (float*)(ws + 0);
    float* t1    = (float*)(ws + 2048);
    float* s2    = (float*)(ws + 4096);
    float* t2    = (float*)(ws + 5120);
    int*   rbfc  = (int*)(ws + 6144);          // 4 KB
    int*   rb1dt = (int*)(ws + 10240);         // 15 KB
    int*   rb1t  = (int*)(ws + 25600);         // 355 KB
    int*   rb2t  = (int*)(ws + 380416);        // 355 KB -> 735232
    // R_A rotating @ [768000, 60930048): fml -> part1 -> part2 -> part1d -> partfc
    bf16*  fml    = (bf16*)(ws + 768000);
    float* part1  = (float*)(ws + 768000);     // 3 x 9792 x 512 x 4 = 60.16 MB
    float* part2  = (float*)(ws + 768000);     // 6 x 9792 x 256 x 4 = 60.16 MB
    float* part1d = (float*)(ws + 768000);     // 4 x 1280 x 2304 x 4 = 47.2 MB
    float* partfc = (float*)(ws + 768000);     // 6 x 1024 x 1024 x 4 = 25.2 MB
    // R_B @ 60930048: a1c (zp1 + compact 1088x9x1024) live roi->conv1; then overlaid:
    bf16*  a1c    = (bf16*)(ws + 60930048);    // 2 KB zp + 20.05 MB
    bf16*  wb1d   = (bf16*)(ws + 60930048);    // 31.85 MB (repacked after conv1)
    bf16*  fc1t   = (bf16*)(ws + 92780544);    // 4.72 MB
    bf16*  xbuf   = (bf16*)(ws + 97499136);    // 5.90 MB
    bf16*  hbuf   = (bf16*)(ws + 103397376);   // 2.10 MB
    bf16*  w2t    = (bf16*)(ws + 105494528);   // 61 KB
    // dedicated
    bf16*  wb1    = (bf16*)(ws + 105555968);   // 9.44 MB
    bf16*  wb2    = (bf16*)(ws + 114993152);   // 2.36 MB
    bf16*  a2c    = (bf16*)(ws + 117352448);   // 1 KB zp + 10.03 MB
    bf16*  asm3   = (bf16*)(ws + 127380480);   // 4.6 KB zp + 5.90 MB
    float* feat   = (float*)(ws + 133283328);  // 10.03 MB -> 143310336

    bf16* zp1 = a1c;           // zero pages = buffer prefixes
    bf16* zp2 = a2c;
    bf16* zp3 = asm3;

    // tables + zero pages + BN folds (one dispatch; no big memsets anymore)
    setup_all<<<(9 * 9856 + 255) / 256, 256, 0, stream>>>(rb1t, rb2t, rb1dt, rbfc, pidx,
                                                          zp1, zp2, zp3,
                                                          bn1_g, bn1_b, bn1_m, bn1_v,
                                                          bn2_g, bn2_b, bn2_m, bn2_v,
                                                          s1, t1, s2, t2);
    repack_w<9><<<(512 * 1024 + 255) / 256, 256, 0, stream>>>(conv1_w, wb1, 512, 1024);
    repack_w<9><<<(256 * 512 + 255) / 256, 256, 0, stream>>>(conv2_w, wb2, 256, 512);

    transpose_fmap<<<dim3(7, 32, 64), dim3(32, 8), 0, stream>>>(fmap, fml);
    roi_kernel2<<<1088, 128, 0, stream>>>(fml, boxes, a1c);

    // conv1: M=9792 N=512 K=9216, split-K x3 -> 924 blocks
    gemm_k<0, 3><<<dim3(4, 77, 3), 256, 0, stream>>>(a1c, rb1t, wb1, part1);
    reduce_k<3><<<(9792 * 512 + 255) / 256, 256, 0, stream>>>(part1, a2c, s1, t1);

    // prep overlaying dead a1c (after conv1)
    repack_w<3><<<(2304 * 2304 + 255) / 256, 256, 0, stream>>>(conv1d_w, wb1d, 2304, 2304);
    transpose_fc1<<<dim3(72, 32), dim3(32, 8), 0, stream>>>(fc1_w, fc1t);
    transpose_w2<<<(30 * 1024 + 255) / 256, 256, 0, stream>>>(fc2_w, w2t);

    // conv2: M=9792 N=256 K=4608, split-K x6 -> 924 blocks
    gemm_k<1, 6><<<dim3(2, 77, 6), 256, 0, stream>>>(a2c, rb2t, wb2, part2);
    reduce_k<0><<<(9792 * 256 + 255) / 256, 256, 0, stream>>>(part2, feat, s2, t2);
    assemble<<<dim3(64, 20), 256, 0, stream>>>(feat, pidx, asm3);
    // conv1d: M=1280 N=2304 K=6912, split-K x4 -> 720 blocks
    gemm_k<2, 4><<<dim3(18, 10, 4), 256, 0, stream>>>(asm3, rb1dt, wb1d, part1d);
    reduce_k<1><<<(1280 * 2304 + 255) / 256, 256, 0, stream>>>(part1d, xbuf, conv1d_b, nullptr);
    // fc1: M=1024 N=1024 K=2304, split-K x6 -> 384 blocks
    gemm_k<3, 6><<<dim3(8, 8, 6), 256, 0, stream>>>(xbuf, rbfc, fc1t, partfc);
    reduce_k<2><<<(1024 * 1024 + 255) / 256, 256, 0, stream>>>(partfc, hbuf, fc1_b, nullptr);
    fc2_kernel<<<128, 256, 0, stream>>>(hbuf, w2t, fc2_b, out);
    (void)in_sizes; (void)n_in; (void)out_size; (void)ws_size;
}

// Round 8
// 483.631 us; speedup vs baseline: 2.6477x; 1.0398x over previous
//
#include <hip/hip_runtime.h>
#include <hip/hip_bf16.h>
#include <cstdint>
#include <cstddef>

typedef __bf16 bf16;
typedef __bf16 bf16x8 __attribute__((ext_vector_type(8)));
typedef float f32x4 __attribute__((ext_vector_type(4)));

// async global->LDS DMA, 16B per lane; lds dest wave-uniform base + lane*16
__device__ __forceinline__ void gload_lds16(const bf16* g, bf16* l) {
    __builtin_amdgcn_global_load_lds((const __attribute__((address_space(1))) void*)g,
                                     (__attribute__((address_space(3))) void*)l, 16, 0, 0);
}

// ---------------- weight repack (coalesced): w[OC][IC][NT] -> out[OC][NT*IC] bf16
template <int NT>
__global__ void __launch_bounds__(256) repack_w(const float* __restrict__ w, bf16* __restrict__ out,
                                                int OC, int IC) {
    int idx = blockIdx.x * 256 + threadIdx.x;
    if (idx >= OC * IC) return;
    int oc = idx / IC;
    int ic = idx - oc * IC;
    const float* src = w + (size_t)idx * NT;
    #pragma unroll
    for (int t = 0; t < NT; t++)
        out[(size_t)oc * NT * IC + t * IC + ic] = (bf16)src[t];
}

// ---------------- fc1_w [2304][1024] -> fc1t [1024][2304] bf16 (LDS tiled)
__global__ void __launch_bounds__(256) transpose_fc1(const float* __restrict__ w, bf16* __restrict__ out) {
    __shared__ float t[32][33];
    int iT = blockIdx.x * 32;
    int oT = blockIdx.y * 32;
    int tx = threadIdx.x, ty = threadIdx.y;   // 32 x 8
    #pragma unroll
    for (int j = 0; j < 4; j++)
        t[ty + j * 8][tx] = w[(size_t)(iT + ty + j * 8) * 1024 + oT + tx];
    __syncthreads();
    #pragma unroll
    for (int j = 0; j < 4; j++)
        out[(size_t)(oT + ty + j * 8) * 2304 + iT + tx] = (bf16)t[tx][ty + j * 8];
}

// ---------------- unified setup: per-tap rowbase tables, zero pages, BN folds, w2t
// rb1t/rb2t[9][9856]: conv1/conv2 taps (invalid -> 0 = zero page)
// rb1dg[3][1024]: conv1d taps at GATHERED rows m=(b*16+n) -> (p=pidx, t=b+tap-1)
// rbid[1024]: identity rows for fc1
__global__ void __launch_bounds__(256) setup_all(int* __restrict__ rb1t, int* __restrict__ rb2t,
                                                 int* __restrict__ rb1dg, int* __restrict__ rbid,
                                                 const int* __restrict__ pidx,
                                                 bf16* __restrict__ zp1, bf16* __restrict__ zp2,
                                                 bf16* __restrict__ zp3,
                                                 const float* g1, const float* b1, const float* m1, const float* v1,
                                                 const float* g2, const float* b2, const float* m2, const float* v2,
                                                 float* __restrict__ s1, float* __restrict__ t1,
                                                 float* __restrict__ s2, float* __restrict__ t2,
                                                 const float* __restrict__ fc2_w, bf16* __restrict__ w2t) {
    int m = blockIdx.x * 256 + threadIdx.x;
    if (m < 9 * 9856) {
        int tap = m / 9856, r = m - tap * 9856;
        int mm = r < 9792 ? r : 0;
        int img = mm / 9, pos = mm - img * 9;
        int oy = pos / 3, ox = pos - oy * 3;
        int ty = tap / 3, tx = tap - ty * 3;
        int iy = oy + ty - 1, ix = ox + tx - 1;
        bool valid = (iy >= 0) & (iy < 3) & (ix >= 0) & (ix < 3);
        int cell = img * 9 + iy * 3 + ix;
        rb1t[m] = valid ? 1024 + cell * 1024 : 0;
        rb2t[m] = valid ? 512 + cell * 512 : 0;
    }
    if (m < 3 * 1024) {
        int tap = m / 1024, r = m - tap * 1024;
        int b = r >> 4;
        int p = pidx[r];
        int tt = b + tap - 1;
        bool valid = (tt >= 0) & (tt < 64);
        rb1dg[m] = valid ? 2304 + (p * 64 + tt) * 2304 : 0;
    }
    if (m < 1024) rbid[m] = m * 2304;
    if (m < 30 * 1024) {
        int n = m / 1024, k = m - n * 1024;
        w2t[m] = (bf16)fc2_w[(size_t)k * 30 + n];
    }
    if (m < 1024) zp1[m] = (bf16)0.f;
    if (m < 512)  zp2[m] = (bf16)0.f;
    if (m < 2304) zp3[m] = (bf16)0.f;
    if (m < 512) {
        float sc = g1[m] * rsqrtf(v1[m] + 1e-5f);
        s1[m] = sc; t1[m] = b1[m] - m1[m] * sc;
    } else if (m < 768) {
        int i = m - 512;
        float sc = g2[i] * rsqrtf(v2[i] + 1e-5f);
        s2[i] = sc; t2[i] = b2[i] - m2[i] * sc;
    }
}

// ---------------- fmap transpose to channels-last bf16
__global__ void __launch_bounds__(256) transpose_fmap(const float* __restrict__ fmap, bf16* __restrict__ fml) {
    __shared__ float t[32][33];
    int img = blockIdx.z;
    int hwT = blockIdx.x * 32;
    int cT  = blockIdx.y * 32;
    int tx = threadIdx.x, ty = threadIdx.y;
    #pragma unroll
    for (int j = 0; j < 4; j++) {
        int c = cT + ty + j * 8;
        int hw = hwT + tx;
        if (hw < 196)
            t[ty + j * 8][tx] = fmap[((size_t)img * 1024 + c) * 196 + hw];
    }
    __syncthreads();
    #pragma unroll
    for (int j = 0; j < 4; j++) {
        int hw = hwT + ty + j * 8;
        int c = cT + tx;
        if (hw < 196)
            fml[((size_t)img * 196 + hw) * 1024 + c] = (bf16)t[tx][ty + j * 8];
    }
}

// ---------------- roi_align (channels-last) -> a1c compact [1088][9][1024] (after 1024-elem zp)
__global__ void __launch_bounds__(128) roi_kernel2(const bf16* __restrict__ fml, const float* __restrict__ boxes,
                                                   bf16* __restrict__ a1c) {
    int box = blockIdx.x;
    int tid = threadIdx.x;
    float x1, y1, x2, y2;
    int img;
    if (box < 64) { img = box; x1 = 0.f; y1 = 0.f; x2 = 14.f; y2 = 14.f; }
    else {
        int ib = box - 64;
        img = ib >> 4;
        const float* bb = boxes + (size_t)ib * 4;
        x1 = bb[0]; y1 = bb[1]; x2 = bb[2]; y2 = bb[3];
    }
    float rw = fmaxf(x2 - x1, 1.f), rh = fmaxf(y2 - y1, 1.f);
    __shared__ float swy[6], swx[6];
    __shared__ int sy0[6], sx0[6];
    if (tid < 6) {
        int i = tid;
        float pos = ((float)i + 0.5f) * 0.5f;
        float yv = fminf(fmaxf(y1 + pos * (rh * (1.f / 3.f)), 0.f), 13.f);
        float y0 = floorf(yv);
        sy0[i] = (int)y0; swy[i] = yv - y0;
        float xv = fminf(fmaxf(x1 + pos * (rw * (1.f / 3.f)), 0.f), 13.f);
        float x0 = floorf(xv);
        sx0[i] = (int)x0; swx[i] = xv - x0;
    }
    __syncthreads();
    const bf16* base = fml + (size_t)img * 196 * 1024 + tid * 8;
    #pragma unroll
    for (int oy = 0; oy < 3; oy++) {
        #pragma unroll
        for (int ox = 0; ox < 3; ox++) {
            float acc[8];
            #pragma unroll
            for (int e = 0; e < 8; e++) acc[e] = 0.f;
            #pragma unroll
            for (int dy = 0; dy < 2; dy++) {
                int sy = 2 * oy + dy;
                int y0 = sy0[sy]; float wy = swy[sy];
                int y1i = min(y0 + 1, 13);
                #pragma unroll
                for (int dx = 0; dx < 2; dx++) {
                    int sx = 2 * ox + dx;
                    int x0 = sx0[sx]; float wx = swx[sx];
                    int x1i = min(x0 + 1, 13);
                    bf16x8 f00 = *(const bf16x8*)(base + (size_t)(y0 * 14 + x0) * 1024);
                    bf16x8 f01 = *(const bf16x8*)(base + (size_t)(y0 * 14 + x1i) * 1024);
                    bf16x8 f10 = *(const bf16x8*)(base + (size_t)(y1i * 14 + x0) * 1024);
                    bf16x8 f11 = *(const bf16x8*)(base + (size_t)(y1i * 14 + x1i) * 1024);
                    float w00 = (1.f - wy) * (1.f - wx), w01 = (1.f - wy) * wx;
                    float w10 = wy * (1.f - wx),         w11 = wy * wx;
                    #pragma unroll
                    for (int e = 0; e < 8; e++)
                        acc[e] += w00 * (float)f00[e] + w01 * (float)f01[e]
                                + w10 * (float)f10[e] + w11 * (float)f11[e];
                }
            }
            bf16x8 o;
            #pragma unroll
            for (int e = 0; e < 8; e++) o[e] = (bf16)(acc[e] * 0.25f);
            *(bf16x8*)(a1c + 1024 + ((size_t)box * 9 + oy * 3 + ox) * 1024 + tid * 8) = o;
        }
    }
}

// ---------------- behavior assembly -> asm3 compact [20][64][2304] (after 2304-elem zp)
__global__ void __launch_bounds__(256) assemble(const float* __restrict__ feat, const int* __restrict__ pidx,
                                                bf16* __restrict__ asm3) {
    int b = blockIdx.x;
    int p = blockIdx.y;
    __shared__ int idxs[16];
    if (threadIdx.x < 16) idxs[threadIdx.x] = pidx[b * 16 + threadIdx.x];
    __syncthreads();
    const float* g = feat + (size_t)b * 2304;
    for (int f = threadIdx.x; f < 2304; f += 256) {
        float v = g[f];
        #pragma unroll
        for (int n = 0; n < 16; n++)
            if (idxs[n] == p) v += feat[(size_t)(64 + b * 16 + n) * 2304 + f];
        asm3[2304 + ((size_t)p * 64 + b) * 2304 + f] = (bf16)v;
    }
}

// ---------------- implicit-GEMM MFMA: 128x128 tile, global_load_lds + XOR swizzle,
// per-tap row tables (zero rows -> zero page). 4 waves 2x2; wave 64x64
// (4x4 16x16x32, acc[4][4]); BK=64; split-K fp32 partials.
template <int MODE, int NSPLIT>
__global__ void __launch_bounds__(256) gemm_k(const bf16* __restrict__ A, const int* __restrict__ rowtab,
                                              const bf16* __restrict__ Bw, float* __restrict__ outp) {
    constexpr int K   = MODE == 0 ? 9216 : MODE == 1 ? 4608 : MODE == 2 ? 6912 : 2304;
    constexpr int N   = MODE == 0 ? 512  : MODE == 1 ? 256  : MODE == 2 ? 2304 : 1024;
    constexpr int Cin = MODE == 0 ? 1024 : MODE == 1 ? 512  : 2304;
    constexpr int M   = MODE <= 1 ? 9792 : 1024;
    constexpr int MT  = MODE <= 1 ? 9856 : 1024;   // table row stride
    constexpr bool MPAD = (M % 128) != 0;
    constexpr int KTS = (K / 64) / NSPLIT;

    const int bm = blockIdx.y * 128;
    const int bn = blockIdx.x * 128;
    const int z  = blockIdx.z;
    const int tid = threadIdx.x;
    const int lane = tid & 63, wave = tid >> 6;
    const int q = lane >> 4, ln16 = lane & 15;
    const int wr = wave >> 1, wc = wave & 1;

    __shared__ __align__(16) bf16 As[128 * 64];
    __shared__ __align__(16) bf16 Bs[128 * 64];

    const int sr = lane >> 3;
    const int sc = ((lane & 7) ^ sr) * 8;    // XOR-permuted chunk offset (elems)
    const bf16* gB[4];
    #pragma unroll
    for (int u = 0; u < 4; u++)
        gB[u] = Bw + (size_t)(bn + wave * 32 + u * 8 + sr) * K + sc;

    f32x4 acc[4][4];
    #pragma unroll
    for (int mt = 0; mt < 4; mt++)
        #pragma unroll
        for (int nt = 0; nt < 4; nt++)
            acc[mt][nt] = (f32x4){0.f, 0.f, 0.f, 0.f};

    int rbA[4];
    int curtap = -1;
    for (int kt = z * KTS; kt < z * KTS + KTS; kt++) {
        const int k0 = kt * 64;
        const int tap = k0 / Cin;                 // wave-uniform
        const int inner = k0 - tap * Cin;
        if (tap != curtap) {
            curtap = tap;
            #pragma unroll
            for (int u = 0; u < 4; u++)
                rbA[u] = rowtab[tap * MT + bm + wave * 32 + u * 8 + sr];
        }
        const int aoff = inner + sc;

        __syncthreads();
        #pragma unroll
        for (int u = 0; u < 4; u++)
            gload_lds16(A + (size_t)(rbA[u] + aoff), As + (wave * 32 + u * 8) * 64);
        #pragma unroll
        for (int u = 0; u < 4; u++)
            gload_lds16(gB[u] + k0, Bs + (wave * 32 + u * 8) * 64);
        __syncthreads();

        #pragma unroll
        for (int s = 0; s < 2; s++) {
            bf16x8 af[4], bfr[4];
            #pragma unroll
            for (int mt = 0; mt < 4; mt++) {
                int r = wr * 64 + mt * 16 + ln16;
                af[mt] = *(const bf16x8*)(As + r * 64 + (((4 * s + q) ^ (ln16 & 7)) << 3));
            }
            #pragma unroll
            for (int nt = 0; nt < 4; nt++) {
                int r = wc * 64 + nt * 16 + ln16;
                bfr[nt] = *(const bf16x8*)(Bs + r * 64 + (((4 * s + q) ^ (ln16 & 7)) << 3));
            }
            #pragma unroll
            for (int mt = 0; mt < 4; mt++)
                #pragma unroll
                for (int nt = 0; nt < 4; nt++)
                    acc[mt][nt] = __builtin_amdgcn_mfma_f32_16x16x32_bf16(af[mt], bfr[nt], acc[mt][nt], 0, 0, 0);
        }
    }

    // epilogue: C/D layout col=lane&15, row=quad*4+reg; fp32 partials
    #pragma unroll
    for (int mt = 0; mt < 4; mt++) {
        int gmBase = bm + wr * 64 + mt * 16 + q * 4;
        #pragma unroll
        for (int r = 0; r < 4; r++) {
            int gm = gmBase + r;
            if (MPAD && gm >= M) continue;
            #pragma unroll
            for (int nt = 0; nt < 4; nt++) {
                int gn = bn + wc * 64 + nt * 16 + ln16;
                outp[((size_t)z * M + gm) * N + gn] = acc[mt][nt][r];
            }
        }
    }
}

// ---------------- conv2 reducer: per-cell block, coalesced + LDS transpose
// part2[6][9792][256] -> feat[1088][2304] fp32 with BN+leaky, f = oc*9+pos
__global__ void __launch_bounds__(256) reduce0_tiled(const float* __restrict__ part,
                                                     float* __restrict__ feat,
                                                     const float* __restrict__ s2, const float* __restrict__ t2) {
    int c = blockIdx.x;            // cell 0..1087
    int t = threadIdx.x;           // oc
    float acc[9];
    #pragma unroll
    for (int r = 0; r < 9; r++) acc[r] = 0.f;
    #pragma unroll
    for (int z = 0; z < 6; z++) {
        const float* base = part + ((size_t)z * 9792 + c * 9) * 256 + t;
        #pragma unroll
        for (int r = 0; r < 9; r++) acc[r] += base[r * 256];
    }
    float s = s2[t], b = t2[t];
    __shared__ float L[9 * 257];
    #pragma unroll
    for (int r = 0; r < 9; r++) {
        float v = acc[r] * s + b;
        v = v > 0.f ? v : 0.1f * v;
        L[r * 257 + t] = v;        // L[pos*257 + oc]
    }
    __syncthreads();
    float* fout = feat + (size_t)c * 2304;
    #pragma unroll
    for (int k = 0; k < 9; k++) {
        int f = t + k * 256;
        int oc = f / 9, pos = f - oc * 9;
        fout[f] = L[pos * 257 + oc];
    }
}

// ---------------- split-K reducers
// RMODE 1: conv1d -> xbuf bf16 (+bias, linear [m=(b,n)][oc]), S=4, M=1024 N=2304
// RMODE 2: fc1 -> hbuf bf16 (+bias, relu), S=6, M=1024 N=1024
// RMODE 3: conv1 -> a2c compact bf16 (BN+leaky, +zp offset), S=3, M=9792 N=512
template <int RMODE>
__global__ void __launch_bounds__(256) reduce_k(const float* __restrict__ part, void* __restrict__ outp,
                                                const float* __restrict__ c0, const float* __restrict__ c1) {
    constexpr int M = RMODE == 1 ? 1024 : RMODE == 2 ? 1024 : 9792;
    constexpr int N = RMODE == 1 ? 2304 : RMODE == 2 ? 1024 : 512;
    constexpr int S = RMODE == 1 ? 4    : RMODE == 2 ? 6    : 3;
    int idx = blockIdx.x * 256 + threadIdx.x;
    if (idx >= M * N) return;
    int m = idx / N, n = idx - m * N;
    float v = 0.f;
    #pragma unroll
    for (int s = 0; s < S; s++) v += part[(size_t)s * M * N + idx];
    if constexpr (RMODE == 1) {
        v += c0[n];
        ((bf16*)outp)[idx] = (bf16)v;
    } else if constexpr (RMODE == 2) {
        v = fmaxf(v + c0[n], 0.f);
        ((bf16*)outp)[idx] = (bf16)v;
    } else {
        v = v * c0[n] + c1[n];
        v = v > 0.f ? v : 0.1f * v;
        ((bf16*)outp)[512 + (size_t)m * 512 + n] = (bf16)v;   // compact, after zp2
    }
}

// ---------------- fc2
__global__ void __launch_bounds__(256) fc2_kernel(const bf16* __restrict__ h, const bf16* __restrict__ w2t,
                                                  const float* __restrict__ b2, float* __restrict__ out) {
    int tid = threadIdx.x;
    int m = blockIdx.x * 8 + (tid >> 5);
    int n = tid & 31;
    int n2 = n < 30 ? n : 29;
    const bf16* hr = h + (size_t)m * 1024;
    const bf16* wr = w2t + (size_t)n2 * 1024;
    float acc = 0.f;
    for (int k = 0; k < 1024; k += 8) {
        bf16x8 hv = *(const bf16x8*)(hr + k);
        bf16x8 wv = *(const bf16x8*)(wr + k);
        #pragma unroll
        for (int e = 0; e < 8; e++) acc += (float)hv[e] * (float)wv[e];
    }
    if (n < 30) out[(size_t)m * 30 + n] = acc + b2[n];
}

extern "C" void kernel_launch(void* const* d_in, const int* in_sizes, int n_in,
                              void* d_out, int out_size, void* d_ws, size_t ws_size,
                              hipStream_t stream) {
    const float* fmap     = (const float*)d_in[0];
    const float* boxes    = (const float*)d_in[1];
    const int*   pidx     = (const int*)d_in[2];
    const float* conv1_w  = (const float*)d_in[3];
    const float* bn1_g    = (const float*)d_in[4];
    const float* bn1_b    = (const float*)d_in[5];
    const float* bn1_m    = (const float*)d_in[6];
    const float* bn1_v    = (const float*)d_in[7];
    const float* conv2_w  = (const float*)d_in[8];
    const float* bn2_g    = (const float*)d_in[9];
    const float* bn2_b    = (const float*)d_in[10];
    const float* bn2_m    = (const float*)d_in[11];
    const float* bn2_v    = (const float*)d_in[12];
    const float* conv1d_w = (const float*)d_in[13];
    const float* conv1d_b = (const float*)d_in[14];
    const float* fc1_w    = (const float*)d_in[15];
    const float* fc1_b    = (const float*)d_in[16];
    const float* fc2_w    = (const float*)d_in[17];
    const float* fc2_b    = (const float*)d_in[18];
    float* out = (float*)d_out;

    char* ws = (char*)d_ws;

    // ---- arena (peak ~142.6 MB; proven budget >= 171.7 MB) ----
    float* s1    = (float*)(ws + 0);
    float* t1    = (float*)(ws + 2048);
    float* s2    = (float*)(ws + 4096);
    float* t2    = (float*)(ws + 5120);
    int*   rbid  = (int*)(ws + 6144);          // 4 KB identity (fc1)
    int*   rb1dg = (int*)(ws + 10240);         // 12 KB gathered conv1d taps
    int*   rb1t  = (int*)(ws + 25600);         // 355 KB
    int*   rb2t  = (int*)(ws + 380416);        // 355 KB -> 735232
    // R_A rotating @ [768000, 60930048): fml -> part1 -> part2 -> part1d -> partfc
    bf16*  fml    = (bf16*)(ws + 768000);
    float* part1  = (float*)(ws + 768000);     // 3 x 9792 x 512 x 4 = 60.16 MB (exact)
    float* part2  = (float*)(ws + 768000);     // 6 x 9792 x 256 x 4 = 60.16 MB (exact)
    float* part1d = (float*)(ws + 768000);     // 4 x 1024 x 2304 x 4 = 37.75 MB
    float* partfc = (float*)(ws + 768000);     // 6 x 1024 x 1024 x 4 = 25.2 MB
    // R_B @ 60930048: a1c (zp1 + compact 1088x9x1024) live roi->conv1; then overlaid:
    bf16*  a1c    = (bf16*)(ws + 60930048);    // 2 KB zp + 20.05 MB
    bf16*  wb1d   = (bf16*)(ws + 60930048);    // 31.85 MB (repacked after conv1)
    bf16*  fc1t   = (bf16*)(ws + 92780544);    // 4.72 MB
    bf16*  xbuf   = (bf16*)(ws + 97499136);    // 1024x2304x2 = 4.72 MB
    bf16*  hbuf   = (bf16*)(ws + 102217728);   // 2.10 MB
    bf16*  w2t    = (bf16*)(ws + 104314880);   // 61 KB
    // dedicated
    bf16*  wb1    = (bf16*)(ws + 104857600);   // 9.44 MB
    bf16*  wb2    = (bf16*)(ws + 114294784);   // 2.36 MB
    bf16*  a2c    = (bf16*)(ws + 116654080);   // 1 KB zp + 10.03 MB
    bf16*  asm3   = (bf16*)(ws + 126682112);   // 4.6 KB zp + 5.90 MB
    float* feat   = (float*)(ws + 132584960);  // 10.03 MB -> 142611968

    bf16* zp1 = a1c;           // zero pages = buffer prefixes
    bf16* zp2 = a2c;
    bf16* zp3 = asm3;

    // tables + zero pages + BN folds + w2t (one dispatch)
    setup_all<<<(9 * 9856 + 255) / 256, 256, 0, stream>>>(rb1t, rb2t, rb1dg, rbid, pidx,
                                                          zp1, zp2, zp3,
                                                          bn1_g, bn1_b, bn1_m, bn1_v,
                                                          bn2_g, bn2_b, bn2_m, bn2_v,
                                                          s1, t1, s2, t2, fc2_w, w2t);
    repack_w<9><<<(512 * 1024 + 255) / 256, 256, 0, stream>>>(conv1_w, wb1, 512, 1024);
    repack_w<9><<<(256 * 512 + 255) / 256, 256, 0, stream>>>(conv2_w, wb2, 256, 512);

    transpose_fmap<<<dim3(7, 32, 64), dim3(32, 8), 0, stream>>>(fmap, fml);
    roi_kernel2<<<1088, 128, 0, stream>>>(fml, boxes, a1c);

    // conv1: M=9792 N=512 K=9216, split-K x3 -> 924 blocks
    gemm_k<0, 3><<<dim3(4, 77, 3), 256, 0, stream>>>(a1c, rb1t, wb1, part1);
    reduce_k<3><<<(9792 * 512 + 255) / 256, 256, 0, stream>>>(part1, a2c, s1, t1);

    // prep overlaying dead a1c (after conv1)
    repack_w<3><<<(2304 * 2304 + 255) / 256, 256, 0, stream>>>(conv1d_w, wb1d, 2304, 2304);
    transpose_fc1<<<dim3(72, 32), dim3(32, 8), 0, stream>>>(fc1_w, fc1t);

    // conv2: M=9792 N=256 K=4608, split-K x6 -> 924 blocks
    gemm_k<1, 6><<<dim3(2, 77, 6), 256, 0, stream>>>(a2c, rb2t, wb2, part2);
    reduce0_tiled<<<1088, 256, 0, stream>>>(part2, feat, s2, t2);
    assemble<<<dim3(64, 20), 256, 0, stream>>>(feat, pidx, asm3);
    // conv1d at gathered rows: M=1024 N=2304 K=6912, split-K x4 -> 576 blocks
    gemm_k<2, 4><<<dim3(18, 8, 4), 256, 0, stream>>>(asm3, rb1dg, wb1d, part1d);
    reduce_k<1><<<(1024 * 2304 + 255) / 256, 256, 0, stream>>>(part1d, xbuf, conv1d_b, nullptr);
    // fc1 (identity rows): M=1024 N=1024 K=2304, split-K x6 -> 384 blocks
    gemm_k<3, 6><<<dim3(8, 8, 6), 256, 0, stream>>>(xbuf, rbid, fc1t, partfc);
    reduce_k<2><<<(1024 * 1024 + 255) / 256, 256, 0, stream>>>(partfc, hbuf, fc1_b, nullptr);
    fc2_kernel<<<128, 256, 0, stream>>>(hbuf, w2t, fc2_b, out);
    (void)in_sizes; (void)n_in; (void)out_size; (void)ws_size;
}